// Round 1
// baseline (1596.035 us; speedup 1.0000x reference)
//
#include <hip/hip_runtime.h>
#include <hip/hip_bf16.h>
#include <math.h>

// Problem constants
#define BB 2
#define TT 2048
#define DM 1024
#define NH 16
#define HD 64
#define FEAT 16
#define WIN 64
#define RTOT (BB*TT)        // 4096 rows

// ---------------------------------------------------------------------------
// Kernel 1: RMSNorm  h = x * rsqrt(mean(x^2)+eps) * w
// ---------------------------------------------------------------------------
__global__ __launch_bounds__(256) void rmsnorm_kernel(const float* __restrict__ x,
                                                      const float* __restrict__ w,
                                                      float* __restrict__ h) {
    int row = blockIdx.x;
    int tid = threadIdx.x;
    const float4* xr = (const float4*)(x + (size_t)row * DM);
    float4 xv = xr[tid];                       // 256 threads * 4 = 1024
    float ss = xv.x*xv.x + xv.y*xv.y + xv.z*xv.z + xv.w*xv.w;
    #pragma unroll
    for (int off = 32; off > 0; off >>= 1) ss += __shfl_down(ss, off, 64);
    __shared__ float red[4];
    if ((tid & 63) == 0) red[tid >> 6] = ss;
    __syncthreads();
    float tot = red[0] + red[1] + red[2] + red[3];
    float scale = rsqrtf(tot * (1.0f / DM) + 1e-6f);
    float4 wv = ((const float4*)w)[tid];
    float4 o;
    o.x = xv.x * scale * wv.x;
    o.y = xv.y * scale * wv.y;
    o.z = xv.z * scale * wv.z;
    o.w = xv.w * scale * wv.w;
    ((float4*)(h + (size_t)row * DM))[tid] = o;
}

// ---------------------------------------------------------------------------
// Kernel 2: QKV GEMM.  C[z] = h @ W[z],  M=4096 K=1024 N=1024, 64x64 tiles.
// blockIdx.z selects (Wq->q, Wk->k, Wv->v).
// ---------------------------------------------------------------------------
__global__ __launch_bounds__(256) void gemm_qkv_kernel(const float* __restrict__ A,
                                                       const float* __restrict__ Wq,
                                                       const float* __restrict__ Wk,
                                                       const float* __restrict__ Wv,
                                                       float* __restrict__ q,
                                                       float* __restrict__ k,
                                                       float* __restrict__ v) {
    const int K = 1024, N = 1024;
    const float* W = (blockIdx.z == 0) ? Wq : (blockIdx.z == 1) ? Wk : Wv;
    float* C = (blockIdx.z == 0) ? q : (blockIdx.z == 1) ? k : v;

    __shared__ float As[16][68];   // [k][m], padded
    __shared__ float Bs[16][68];   // [k][n], padded

    int tid = threadIdx.x;
    int tx = tid & 15, ty = tid >> 4;
    int m0 = blockIdx.y * 64;
    int n0 = blockIdx.x * 64;

    float acc[4][4];
    #pragma unroll
    for (int i = 0; i < 4; i++)
        #pragma unroll
        for (int j = 0; j < 4; j++) acc[i][j] = 0.f;

    int arow = tid >> 2;           // 0..63
    int akq  = (tid & 3) << 2;     // 0,4,8,12
    int bkr  = tid >> 4;           // 0..15
    int bnq  = (tid & 15) << 2;    // 0..60

    for (int kt = 0; kt < K; kt += 16) {
        float4 av = *(const float4*)&A[(size_t)(m0 + arow) * K + kt + akq];
        float4 bv = *(const float4*)&W[(size_t)(kt + bkr) * N + n0 + bnq];
        As[akq + 0][arow] = av.x;
        As[akq + 1][arow] = av.y;
        As[akq + 2][arow] = av.z;
        As[akq + 3][arow] = av.w;
        *(float4*)&Bs[bkr][bnq] = bv;
        __syncthreads();
        #pragma unroll
        for (int kk = 0; kk < 16; kk++) {
            float4 a = *(float4*)&As[kk][ty << 2];
            float4 b = *(float4*)&Bs[kk][tx << 2];
            float ar[4] = {a.x, a.y, a.z, a.w};
            float br[4] = {b.x, b.y, b.z, b.w};
            #pragma unroll
            for (int i = 0; i < 4; i++)
                #pragma unroll
                for (int j = 0; j < 4; j++) acc[i][j] += ar[i] * br[j];
        }
        __syncthreads();
    }
    #pragma unroll
    for (int i = 0; i < 4; i++) {
        float4 o = {acc[i][0], acc[i][1], acc[i][2], acc[i][3]};
        *(float4*)&C[(size_t)(m0 + (ty << 2) + i) * N + n0 + (tx << 2)] = o;
    }
}

// ---------------------------------------------------------------------------
// Kernel 3: feature projection  qf = q_heads @ Wqf, kf = k_heads @ Wkf
// rows = RTOT*NH of dim HD=64 -> FEAT=16.  blockIdx.z: 0->q, 1->k
// ---------------------------------------------------------------------------
__global__ __launch_bounds__(256) void feat_kernel(const float* __restrict__ q,
                                                   const float* __restrict__ k,
                                                   const float* __restrict__ Wqf,
                                                   const float* __restrict__ Wkf,
                                                   float* __restrict__ qf,
                                                   float* __restrict__ kf) {
    __shared__ float Wl[HD * FEAT];
    const float* src = blockIdx.z ? k : q;
    const float* Wm  = blockIdx.z ? Wkf : Wqf;
    float* dst       = blockIdx.z ? kf : qf;
    int tid = threadIdx.x;
    ((float4*)Wl)[tid] = ((const float4*)Wm)[tid];   // 1024 floats
    __syncthreads();
    int gid = blockIdx.x * 256 + tid;                // over RTOT*NH*FEAT
    int f = gid & 15;
    int rowh = gid >> 4;
    const float* s = src + (size_t)rowh * HD;
    float acc = 0.f;
    #pragma unroll
    for (int d = 0; d < HD; d++) acc += s[d] * Wl[d * FEAT + f];
    dst[gid] = acc;
}

// ---------------------------------------------------------------------------
// Kernel 4: sliding-window attention (online softmax). One wave per (b,t,h).
// Writes into cat[..., 1024 + h*64 + d].
// ---------------------------------------------------------------------------
__global__ __launch_bounds__(64) void window_kernel(const float* __restrict__ q,
                                                    const float* __restrict__ k,
                                                    const float* __restrict__ v,
                                                    float* __restrict__ cat) {
    int l = threadIdx.x;              // head dim lane
    int gb = blockIdx.x;              // (b*T+t)*NH + h
    int h = gb & 15;
    int bt = gb >> 4;                 // b*T + t
    int t = bt & (TT - 1);
    int b = bt >> 11;                 // /2048
    size_t qoff = (size_t)bt * (NH * HD) + h * HD;
    float ql = q[qoff + l] * 0.125f;  // 1/sqrt(64)
    int s0 = (t >= WIN) ? (t - WIN) : 0;
    float m = -1e30f, den = 0.f, acc = 0.f;
    for (int s = s0; s <= t; s++) {
        size_t koff = ((size_t)(b * TT + s)) * (NH * HD) + h * HD;
        float p = ql * k[koff + l];
        #pragma unroll
        for (int off = 1; off < 64; off <<= 1) p += __shfl_xor(p, off, 64);
        float sc = p;
        float nm = fmaxf(m, sc);
        float alpha = __expf(m - nm);
        float wgt = __expf(sc - nm);
        den = den * alpha + wgt;
        acc = acc * alpha + wgt * v[koff + l];
        m = nm;
    }
    cat[(size_t)bt * (2 * DM) + DM + h * HD + l] = acc / den;
}

// ---------------------------------------------------------------------------
// Kernel 5: linear attention via exact identity
//   phi(u).phi(w) = 1 + u.w + 0.25*(u.w)^2
// Causal quadratic attention over 16-dim qf/kf, flash-style 64x64 tiles.
// Writes into cat[..., h*64 + d].
// grid: (T/64, B*NH)
// ---------------------------------------------------------------------------
__global__ __launch_bounds__(256) void lin_kernel(const float* __restrict__ qf,
                                                  const float* __restrict__ kf,
                                                  const float* __restrict__ v,
                                                  float* __restrict__ cat) {
    int tile = blockIdx.x;
    int bh = blockIdx.y;
    int h = bh & 15;
    int b = bh >> 4;
    int tid = threadIdx.x;
    int d = tid & 63;
    int w = tid >> 6;                 // wave id 0..3, rows r = w + 4*j

    __shared__ float Qf[64][16];
    __shared__ float Kf[64][17];      // +1 pad: reads are lane-varying rows
    __shared__ float Vs[64][64];
    __shared__ float As[64][64];

    int t0 = tile * 64;
    {   // load Qf tile (64x16)
        int r = tid >> 2, fq = (tid & 3) << 2;
        size_t off = ((size_t)((b * TT + t0 + r) * NH + h)) * FEAT + fq;
        *(float4*)&Qf[r][fq] = *(const float4*)&qf[off];
    }

    float y[16], z[16];
    #pragma unroll
    for (int j = 0; j < 16; j++) { y[j] = 0.f; z[j] = 0.f; }

    int ntiles = tile + 1;
    for (int st = 0; st < ntiles; st++) {
        __syncthreads();   // protect Kf/Vs/As reuse (also covers Qf for st=0)
        {   // load Kf tile (64x16)
            int r = tid >> 2, fq = (tid & 3) << 2;
            size_t off = ((size_t)((b * TT + st * 64 + r) * NH + h)) * FEAT + fq;
            float4 t4 = *(const float4*)&kf[off];
            Kf[r][fq + 0] = t4.x; Kf[r][fq + 1] = t4.y;
            Kf[r][fq + 2] = t4.z; Kf[r][fq + 3] = t4.w;
        }
        {   // load V tile (64x64)
            int c4 = (tid & 15) << 2, rbase = tid >> 4;
            #pragma unroll
            for (int i = 0; i < 4; i++) {
                int r = rbase + (i << 4);
                size_t off = ((size_t)((b * TT + st * 64 + r) * NH + h)) * HD + c4;
                *(float4*)&Vs[r][c4] = *(const float4*)&v[off];
            }
        }
        __syncthreads();

        // score tile: thread handles column s=d, rows w+4j
        float kfr[16];
        #pragma unroll
        for (int f = 0; f < 16; f++) kfr[f] = Kf[d][f];
        bool diag = (st == tile);
        #pragma unroll
        for (int j = 0; j < 16; j++) {
            int r = w + (j << 2);
            const float4* qrow = (const float4*)&Qf[r][0];
            float4 q0 = qrow[0], q1 = qrow[1], q2 = qrow[2], q3 = qrow[3];
            float dot = q0.x*kfr[0] + q0.y*kfr[1] + q0.z*kfr[2] + q0.w*kfr[3]
                      + q1.x*kfr[4] + q1.y*kfr[5] + q1.z*kfr[6] + q1.w*kfr[7]
                      + q2.x*kfr[8] + q2.y*kfr[9] + q2.z*kfr[10]+ q2.w*kfr[11]
                      + q3.x*kfr[12]+ q3.y*kfr[13]+ q3.z*kfr[14]+ q3.w*kfr[15];
            float sc = 1.f + dot + 0.25f * dot * dot;   // = (1 + dot/2)^2
            if (diag && d > r) sc = 0.f;
            As[r][d] = sc;
        }
        __syncthreads();

        // PV + row-sum accumulate
        #pragma unroll 4
        for (int s = 0; s < 64; s += 4) {
            float v0 = Vs[s + 0][d], v1 = Vs[s + 1][d];
            float v2 = Vs[s + 2][d], v3 = Vs[s + 3][d];
            #pragma unroll
            for (int j = 0; j < 16; j++) {
                int r = w + (j << 2);
                float4 a = *(float4*)&As[r][s];
                y[j] += a.x * v0 + a.y * v1 + a.z * v2 + a.w * v3;
                z[j] += a.x + a.y + a.z + a.w;
            }
        }
    }

    #pragma unroll
    for (int j = 0; j < 16; j++) {
        int r = w + (j << 2);
        cat[((size_t)(b * TT + t0 + r)) * (2 * DM) + h * HD + d] = y[j] / (z[j] + 1e-6f);
    }
}

// ---------------------------------------------------------------------------
// Kernel 6: output GEMM + residual.  out = x + cat @ Wout
// M=4096 K=2048 N=1024, 64x64 tiles.
// ---------------------------------------------------------------------------
__global__ __launch_bounds__(256) void gemm_out_kernel(const float* __restrict__ A,
                                                       const float* __restrict__ W,
                                                       const float* __restrict__ resid,
                                                       float* __restrict__ C) {
    const int K = 2048, N = 1024;
    __shared__ float As[16][68];
    __shared__ float Bs[16][68];

    int tid = threadIdx.x;
    int tx = tid & 15, ty = tid >> 4;
    int m0 = blockIdx.y * 64;
    int n0 = blockIdx.x * 64;

    float acc[4][4];
    #pragma unroll
    for (int i = 0; i < 4; i++)
        #pragma unroll
        for (int j = 0; j < 4; j++) acc[i][j] = 0.f;

    int arow = tid >> 2;
    int akq  = (tid & 3) << 2;
    int bkr  = tid >> 4;
    int bnq  = (tid & 15) << 2;

    for (int kt = 0; kt < K; kt += 16) {
        float4 av = *(const float4*)&A[(size_t)(m0 + arow) * K + kt + akq];
        float4 bv = *(const float4*)&W[(size_t)(kt + bkr) * N + n0 + bnq];
        As[akq + 0][arow] = av.x;
        As[akq + 1][arow] = av.y;
        As[akq + 2][arow] = av.z;
        As[akq + 3][arow] = av.w;
        *(float4*)&Bs[bkr][bnq] = bv;
        __syncthreads();
        #pragma unroll
        for (int kk = 0; kk < 16; kk++) {
            float4 a = *(float4*)&As[kk][ty << 2];
            float4 b = *(float4*)&Bs[kk][tx << 2];
            float ar[4] = {a.x, a.y, a.z, a.w};
            float br[4] = {b.x, b.y, b.z, b.w};
            #pragma unroll
            for (int i = 0; i < 4; i++)
                #pragma unroll
                for (int j = 0; j < 4; j++) acc[i][j] += ar[i] * br[j];
        }
        __syncthreads();
    }
    #pragma unroll
    for (int i = 0; i < 4; i++) {
        int m = m0 + (ty << 2) + i;
        float4 rsd = *(const float4*)&resid[(size_t)m * N + n0 + (tx << 2)];
        float4 o = {acc[i][0] + rsd.x, acc[i][1] + rsd.y,
                    acc[i][2] + rsd.z, acc[i][3] + rsd.w};
        *(float4*)&C[(size_t)m * N + n0 + (tx << 2)] = o;
    }
}

// ---------------------------------------------------------------------------
extern "C" void kernel_launch(void* const* d_in, const int* in_sizes, int n_in,
                              void* d_out, int out_size, void* d_ws, size_t ws_size,
                              hipStream_t stream) {
    const float* x      = (const float*)d_in[0];
    const float* norm_w = (const float*)d_in[1];
    const float* Wq     = (const float*)d_in[2];
    const float* Wk     = (const float*)d_in[3];
    const float* Wv     = (const float*)d_in[4];
    const float* Wqf    = (const float*)d_in[5];
    const float* Wkf    = (const float*)d_in[6];
    const float* Wout   = (const float*)d_in[7];
    float* out = (float*)d_out;

    // workspace carve-up (floats)
    float* ws = (float*)d_ws;
    float* h   = ws;                         // 4096*1024
    float* q   = h   + (size_t)RTOT * DM;
    float* k   = q   + (size_t)RTOT * DM;
    float* v   = k   + (size_t)RTOT * DM;
    float* qf  = v   + (size_t)RTOT * DM;    // 4096*16*16
    float* kf  = qf  + (size_t)RTOT * NH * FEAT;
    float* cat = kf  + (size_t)RTOT * NH * FEAT;  // 4096*2048

    // 1. RMSNorm
    rmsnorm_kernel<<<RTOT, 256, 0, stream>>>(x, norm_w, h);
    // 2. QKV GEMMs
    gemm_qkv_kernel<<<dim3(16, 64, 3), 256, 0, stream>>>(h, Wq, Wk, Wv, q, k, v);
    // 3. feature projections
    feat_kernel<<<dim3((RTOT * NH * FEAT) / 256, 1, 2), 256, 0, stream>>>(q, k, Wqf, Wkf, qf, kf);
    // 4. sliding window attention  -> cat[:,1024:]
    window_kernel<<<RTOT * NH, 64, 0, stream>>>(q, k, v, cat);
    // 5. linear attention (exact Taylor identity) -> cat[:,:1024]
    lin_kernel<<<dim3(TT / 64, BB * NH), 256, 0, stream>>>(qf, kf, v, cat);
    // 6. output projection + residual
    gemm_out_kernel<<<dim3(16, 64), 256, 0, stream>>>(cat, Wout, x, out);
}

// Round 2
// 591.808 us; speedup vs baseline: 2.6969x; 2.6969x over previous
//
#include <hip/hip_runtime.h>
#include <math.h>

// Problem constants
#define BB 2
#define TT 2048
#define DM 1024
#define NH 16
#define HD 64
#define FEAT 16
#define WIN 64
#define RTOT (BB*TT)        // 4096 rows

typedef __bf16 bf16x8 __attribute__((ext_vector_type(8)));
typedef float  f32x4  __attribute__((ext_vector_type(4)));
typedef float  f32x16 __attribute__((ext_vector_type(16)));

__device__ __forceinline__ unsigned short f2bf(float f) {
    union { float f; unsigned u; } v; v.f = f;
    unsigned r = v.u + 0x7FFFu + ((v.u >> 16) & 1u);   // RNE
    return (unsigned short)(r >> 16);
}

__device__ __forceinline__ void gl2lds16(const void* g, void* l) {
    __builtin_amdgcn_global_load_lds(
        (const __attribute__((address_space(1))) void*)g,
        (__attribute__((address_space(3))) void*)l, 16, 0, 0);
}

// ---------------------------------------------------------------------------
// Kernel 1: RMSNorm -> bf16 output
// ---------------------------------------------------------------------------
__global__ __launch_bounds__(256) void rmsnorm_kernel(const float* __restrict__ x,
                                                      const float* __restrict__ w,
                                                      unsigned short* __restrict__ h_bf) {
    int row = blockIdx.x;
    int tid = threadIdx.x;
    const float4* xr = (const float4*)(x + (size_t)row * DM);
    float4 xv = xr[tid];
    float ss = xv.x*xv.x + xv.y*xv.y + xv.z*xv.z + xv.w*xv.w;
    #pragma unroll
    for (int off = 32; off > 0; off >>= 1) ss += __shfl_down(ss, off, 64);
    __shared__ float red[4];
    if ((tid & 63) == 0) red[tid >> 6] = ss;
    __syncthreads();
    float tot = red[0] + red[1] + red[2] + red[3];
    float scale = rsqrtf(tot * (1.0f / DM) + 1e-6f);
    float4 wv = ((const float4*)w)[tid];
    ushort4 o;
    o.x = f2bf(xv.x * scale * wv.x);
    o.y = f2bf(xv.y * scale * wv.y);
    o.z = f2bf(xv.z * scale * wv.z);
    o.w = f2bf(xv.w * scale * wv.w);
    *(ushort4*)&h_bf[(size_t)row * DM + tid * 4] = o;
}

// ---------------------------------------------------------------------------
// Kernel 2: transpose + fp32->bf16 convert.  W [K][N] fp32 -> WT [N][K] bf16
// grid (N/64, K/64), block 256
// ---------------------------------------------------------------------------
__global__ __launch_bounds__(256) void transpose_bf16_kernel(const float* __restrict__ W,
                                                             unsigned short* __restrict__ WT,
                                                             int K, int N) {
    __shared__ float tile[64][65];
    int k0 = blockIdx.y * 64, n0 = blockIdx.x * 64;
    int t = threadIdx.x;
    int r = t >> 4, c4 = (t & 15) * 4;
    #pragma unroll
    for (int i = 0; i < 4; i++) {
        float4 vv = *(const float4*)&W[(size_t)(k0 + r + i*16) * N + n0 + c4];
        tile[r + i*16][c4 + 0] = vv.x;
        tile[r + i*16][c4 + 1] = vv.y;
        tile[r + i*16][c4 + 2] = vv.z;
        tile[r + i*16][c4 + 3] = vv.w;
    }
    __syncthreads();
    int rn = t >> 2, kq = (t & 3) * 16;
    unsigned short u[16];
    #pragma unroll
    for (int i = 0; i < 16; i++) u[i] = f2bf(tile[kq + i][rn]);
    size_t base = (size_t)(n0 + rn) * K + k0 + kq;
    *(uint4*)&WT[base]     = *(uint4*)&u[0];
    *(uint4*)&WT[base + 8] = *(uint4*)&u[8];
}

// ---------------------------------------------------------------------------
// bf16 MFMA GEMM core: C[M][1024] = A[M][K](bf16) @ BT[1024][K](bf16)^T
// 128x128 tile, BK=32, global_load_lds staging with XOR k-chunk permutation.
// ---------------------------------------------------------------------------
__device__ __forceinline__ void gemm_core(const unsigned short* __restrict__ A,
                                          const unsigned short* __restrict__ BT,
                                          float* __restrict__ C,
                                          const float* __restrict__ resid,
                                          int K) {
    const int N = 1024;
    __shared__ __align__(16) unsigned short As[128 * 32];
    __shared__ __align__(16) unsigned short Bs[128 * 32];
    int tid = threadIdx.x;
    int lane = tid & 63;
    int w = tid >> 6;
    int wm = (w >> 1) * 64, wn = (w & 1) * 64;
    int m0 = blockIdx.y * 128, n0 = blockIdx.x * 128;
    int hi = lane >> 4;

    f32x4 acc[4][4];
    #pragma unroll
    for (int i = 0; i < 4; i++)
        #pragma unroll
        for (int j = 0; j < 4; j++)
            acc[i][j] = (f32x4){0.f, 0.f, 0.f, 0.f};

    for (int kt = 0; kt < K; kt += 32) {
        __syncthreads();
        #pragma unroll
        for (int half = 0; half < 2; half++) {
            int c = tid + half * 256;
            int row = c >> 2, pos = c & 3;
            int kh = (pos - (row >> 1)) & 3;          // global k-chunk stored at pos
            gl2lds16(A  + (size_t)(m0 + row) * K + kt + kh * 8, &As[c * 8]);
            gl2lds16(BT + (size_t)(n0 + row) * K + kt + kh * 8, &Bs[c * 8]);
        }
        __syncthreads();
        bf16x8 af[4], bfr[4];
        #pragma unroll
        for (int i = 0; i < 4; i++) {
            int m = wm + i * 16 + (lane & 15);
            af[i]  = *(const bf16x8*)&As[m * 32 + (((hi + (m >> 1)) & 3) * 8)];
            int n = wn + i * 16 + (lane & 15);
            bfr[i] = *(const bf16x8*)&Bs[n * 32 + (((hi + (n >> 1)) & 3) * 8)];
        }
        #pragma unroll
        for (int i = 0; i < 4; i++)
            #pragma unroll
            for (int j = 0; j < 4; j++)
                acc[i][j] = __builtin_amdgcn_mfma_f32_16x16x32_bf16(af[i], bfr[j], acc[i][j], 0, 0, 0);
    }
    // epilogue: C/D layout col=lane&15, row=(lane>>4)*4+reg
    #pragma unroll
    for (int i = 0; i < 4; i++) {
        #pragma unroll
        for (int j = 0; j < 4; j++) {
            int col = n0 + wn + j * 16 + (lane & 15);
            #pragma unroll
            for (int r = 0; r < 4; r++) {
                int row = m0 + wm + i * 16 + hi * 4 + r;
                float vv = acc[i][j][r];
                if (resid) vv += resid[(size_t)row * N + col];
                C[(size_t)row * N + col] = vv;
            }
        }
    }
}

__global__ __launch_bounds__(256) void gemm_qkv_mfma(const unsigned short* __restrict__ A,
                                                     const unsigned short* __restrict__ BT0,
                                                     const unsigned short* __restrict__ BT1,
                                                     const unsigned short* __restrict__ BT2,
                                                     float* __restrict__ C0,
                                                     float* __restrict__ C1,
                                                     float* __restrict__ C2) {
    const unsigned short* BT = (blockIdx.z == 0) ? BT0 : (blockIdx.z == 1) ? BT1 : BT2;
    float* C = (blockIdx.z == 0) ? C0 : (blockIdx.z == 1) ? C1 : C2;
    gemm_core(A, BT, C, nullptr, 1024);
}

__global__ __launch_bounds__(256) void gemm_out_mfma(const unsigned short* __restrict__ A,
                                                     const unsigned short* __restrict__ BT,
                                                     const float* __restrict__ resid,
                                                     float* __restrict__ C) {
    gemm_core(A, BT, C, resid, 2048);
}

// ---------------------------------------------------------------------------
// Kernel 3: feature projection (fp32, small)
// ---------------------------------------------------------------------------
__global__ __launch_bounds__(256) void feat_kernel(const float* __restrict__ q,
                                                   const float* __restrict__ k,
                                                   const float* __restrict__ Wqf,
                                                   const float* __restrict__ Wkf,
                                                   float* __restrict__ qf,
                                                   float* __restrict__ kf) {
    __shared__ float Wl[HD * FEAT];
    const float* src = blockIdx.z ? k : q;
    const float* Wm  = blockIdx.z ? Wkf : Wqf;
    float* dst       = blockIdx.z ? kf : qf;
    int tid = threadIdx.x;
    ((float4*)Wl)[tid] = ((const float4*)Wm)[tid];
    __syncthreads();
    int gid = blockIdx.x * 256 + tid;
    int f = gid & 15;
    int rowh = gid >> 4;
    const float* s = src + (size_t)rowh * HD;
    float acc = 0.f;
    #pragma unroll
    for (int d = 0; d < HD; d++) acc += s[d] * Wl[d * FEAT + f];
    dst[gid] = acc;
}

// ---------------------------------------------------------------------------
// Kernel 4: sliding-window attention (online softmax), bf16 store into cat_bf
// ---------------------------------------------------------------------------
__global__ __launch_bounds__(64) void window_kernel(const float* __restrict__ q,
                                                    const float* __restrict__ k,
                                                    const float* __restrict__ v,
                                                    unsigned short* __restrict__ cat_bf) {
    int l = threadIdx.x;
    int gb = blockIdx.x;
    int h = gb & 15;
    int bt = gb >> 4;
    int t = bt & (TT - 1);
    int b = bt >> 11;
    size_t qoff = (size_t)bt * (NH * HD) + h * HD;
    float ql = q[qoff + l] * 0.125f;
    int s0 = (t >= WIN) ? (t - WIN) : 0;
    float m = -1e30f, den = 0.f, acc = 0.f;
    for (int s = s0; s <= t; s++) {
        size_t koff = ((size_t)(b * TT + s)) * (NH * HD) + h * HD;
        float p = ql * k[koff + l];
        #pragma unroll
        for (int off = 1; off < 64; off <<= 1) p += __shfl_xor(p, off, 64);
        float sc = p;
        float nm = fmaxf(m, sc);
        float alpha = __expf(m - nm);
        float wgt = __expf(sc - nm);
        den = den * alpha + wgt;
        acc = acc * alpha + wgt * v[koff + l];
        m = nm;
    }
    cat_bf[(size_t)bt * (2 * DM) + DM + h * HD + l] = f2bf(acc / den);
}

// ---------------------------------------------------------------------------
// Kernel 5: linear attention via exact identity, MFMA 32x32x16 flash tiles.
//   phi(u).phi(w) = (1 + u.w/2)^2 ; z accumulated via MFMA against ones.
// grid (32 qtiles reversed, 32 bh), block 256 (4 waves = 2x2 quadrants)
// ---------------------------------------------------------------------------
__global__ __launch_bounds__(256) void lin_mfma_kernel(const float* __restrict__ qf,
                                                       const float* __restrict__ kf,
                                                       const float* __restrict__ v,
                                                       unsigned short* __restrict__ cat_bf) {
    int qtile = 31 - blockIdx.x;      // heavy blocks dispatch first
    int bh = blockIdx.y;
    int h = bh & 15;
    int b = bh >> 4;
    int tid = threadIdx.x;
    int lane = tid & 63;
    int w = tid >> 6;
    int m0 = (w >> 1) * 32;           // query-row quadrant
    int n0 = (w & 1) * 32;            // key-col / dim-col quadrant
    int hi = lane >> 5;

    __shared__ __align__(16) unsigned short Qf_l[64 * 16];
    __shared__ __align__(16) unsigned short Kf_l[64 * 16];
    __shared__ __align__(16) unsigned short Vt_l[64 * 72];  // [dim][key], padded
    __shared__ __align__(16) unsigned short S_l[64 * 72];   // [qrow][key], padded

    // stage Qf tile (64x16) as bf16
    {
        int r = tid >> 2, f = (tid & 3) * 4;
        float4 qv = *(const float4*)&qf[((size_t)((b * TT + qtile * 64 + r) * NH + h)) * FEAT + f];
        ushort4 u; u.x = f2bf(qv.x); u.y = f2bf(qv.y); u.z = f2bf(qv.z); u.w = f2bf(qv.w);
        *(ushort4*)&Qf_l[r * 16 + f] = u;
    }
    __syncthreads();
    bf16x8 aq = *(const bf16x8*)&Qf_l[(m0 + (lane & 31)) * 16 + hi * 8];

    f32x16 yacc, zacc, zro;
    #pragma unroll
    for (int i = 0; i < 16; i++) { yacc[i] = 0.f; zacc[i] = 0.f; zro[i] = 0.f; }
    union { unsigned short u[8]; bf16x8 v; } onesu;
    #pragma unroll
    for (int i = 0; i < 8; i++) onesu.u[i] = 0x3F80;   // bf16 1.0
    bf16x8 ones8 = onesu.v;

    for (int st = 0; st <= qtile; st++) {
        __syncthreads();
        // stage Kf tile (64x16) bf16
        {
            int r = tid >> 2, f = (tid & 3) * 4;
            float4 kv = *(const float4*)&kf[((size_t)((b * TT + st * 64 + r) * NH + h)) * FEAT + f];
            ushort4 u; u.x = f2bf(kv.x); u.y = f2bf(kv.y); u.z = f2bf(kv.z); u.w = f2bf(kv.w);
            *(ushort4*)&Kf_l[r * 16 + f] = u;
        }
        // stage V^T tile (64 dims x 64 keys) bf16: thread = (key pair, dim octet)
        {
            int p = tid & 31, dq = (tid >> 5) * 8;
            size_t base0 = ((size_t)((b * TT + st * 64 + 2 * p) * NH + h)) * HD + dq;
            size_t base1 = base0 + (size_t)NH * HD;
            float4 a0 = *(const float4*)&v[base0];
            float4 a1 = *(const float4*)&v[base0 + 4];
            float4 b0 = *(const float4*)&v[base1];
            float4 b1 = *(const float4*)&v[base1 + 4];
            float va[8] = {a0.x, a0.y, a0.z, a0.w, a1.x, a1.y, a1.z, a1.w};
            float vb[8] = {b0.x, b0.y, b0.z, b0.w, b1.x, b1.y, b1.z, b1.w};
            #pragma unroll
            for (int d = 0; d < 8; d++) {
                ushort2 u; u.x = f2bf(va[d]); u.y = f2bf(vb[d]);
                *(ushort2*)&Vt_l[(dq + d) * 72 + 2 * p] = u;
            }
        }
        __syncthreads();
        // scores: one 32x32x16 MFMA per wave quadrant
        bf16x8 bk = *(const bf16x8*)&Kf_l[(n0 + (lane & 31)) * 16 + hi * 8];
        f32x16 sc = __builtin_amdgcn_mfma_f32_32x32x16_bf16(aq, bk, zro, 0, 0, 0);
        // transform + causal mask + write S_l (bf16)
        bool diag = (st == qtile);
        int colk = n0 + (lane & 31);
        #pragma unroll
        for (int r = 0; r < 16; r++) {
            int rowq = m0 + (r & 3) + 8 * (r >> 2) + 4 * hi;
            float s = 1.f + 0.5f * sc[r];
            s = s * s;                                   // (1 + d/2)^2 = 1 + d + d^2/4
            if (diag && colk > rowq) s = 0.f;
            S_l[rowq * 72 + colk] = f2bf(s);
        }
        __syncthreads();
        // PV (y) + ones-MFMA (z), 4 k-steps over 64 keys
        #pragma unroll
        for (int kt = 0; kt < 4; kt++) {
            bf16x8 as = *(const bf16x8*)&S_l[(m0 + (lane & 31)) * 72 + kt * 16 + hi * 8];
            bf16x8 bv = *(const bf16x8*)&Vt_l[(n0 + (lane & 31)) * 72 + kt * 16 + hi * 8];
            yacc = __builtin_amdgcn_mfma_f32_32x32x16_bf16(as, bv, yacc, 0, 0, 0);
            zacc = __builtin_amdgcn_mfma_f32_32x32x16_bf16(as, ones8, zacc, 0, 0, 0);
        }
    }
    // epilogue: y/z, C layout col=lane&31, row=(r&3)+8*(r>>2)+4*hi
    int dcol = n0 + (lane & 31);
    #pragma unroll
    for (int r = 0; r < 16; r++) {
        int rowq = m0 + (r & 3) + 8 * (r >> 2) + 4 * hi;
        float yv = yacc[r], zv = zacc[r];
        cat_bf[((size_t)(b * TT + qtile * 64 + rowq)) * (2 * DM) + h * 64 + dcol] =
            f2bf(yv / (zv + 1e-6f));
    }
}

// ---------------------------------------------------------------------------
extern "C" void kernel_launch(void* const* d_in, const int* in_sizes, int n_in,
                              void* d_out, int out_size, void* d_ws, size_t ws_size,
                              hipStream_t stream) {
    const float* x      = (const float*)d_in[0];
    const float* norm_w = (const float*)d_in[1];
    const float* Wq     = (const float*)d_in[2];
    const float* Wk     = (const float*)d_in[3];
    const float* Wv     = (const float*)d_in[4];
    const float* Wqf    = (const float*)d_in[5];
    const float* Wkf    = (const float*)d_in[6];
    const float* Wout   = (const float*)d_in[7];
    float* out = (float*)d_out;

    // workspace carve-up
    char* p = (char*)d_ws;
    unsigned short* h_bf  = (unsigned short*)p; p += (size_t)RTOT * DM * 2;       // 8 MB
    unsigned short* WqT   = (unsigned short*)p; p += (size_t)DM * DM * 2;         // 2 MB
    unsigned short* WkT   = (unsigned short*)p; p += (size_t)DM * DM * 2;
    unsigned short* WvT   = (unsigned short*)p; p += (size_t)DM * DM * 2;
    unsigned short* WoT   = (unsigned short*)p; p += (size_t)DM * 2 * DM * 2;     // 4 MB
    float* q   = (float*)p; p += (size_t)RTOT * DM * 4;                           // 16 MB
    float* k   = (float*)p; p += (size_t)RTOT * DM * 4;
    float* v   = (float*)p; p += (size_t)RTOT * DM * 4;
    float* qf  = (float*)p; p += (size_t)RTOT * NH * FEAT * 4;                    // 4 MB
    float* kf  = (float*)p; p += (size_t)RTOT * NH * FEAT * 4;
    unsigned short* cat_bf = (unsigned short*)p; p += (size_t)RTOT * 2 * DM * 2;  // 16 MB

    // 1. RMSNorm (bf16 out)
    rmsnorm_kernel<<<RTOT, 256, 0, stream>>>(x, norm_w, h_bf);
    // 2. weight transposes -> bf16 [N][K]
    transpose_bf16_kernel<<<dim3(16, 16), 256, 0, stream>>>(Wq, WqT, 1024, 1024);
    transpose_bf16_kernel<<<dim3(16, 16), 256, 0, stream>>>(Wk, WkT, 1024, 1024);
    transpose_bf16_kernel<<<dim3(16, 16), 256, 0, stream>>>(Wv, WvT, 1024, 1024);
    transpose_bf16_kernel<<<dim3(16, 32), 256, 0, stream>>>(Wout, WoT, 2048, 1024);
    // 3. QKV GEMMs (bf16 MFMA)
    gemm_qkv_mfma<<<dim3(8, 32, 3), 256, 0, stream>>>(h_bf, WqT, WkT, WvT, q, k, v);
    // 4. feature projections
    feat_kernel<<<dim3((RTOT * NH * FEAT) / 256, 1, 2), 256, 0, stream>>>(q, k, Wqf, Wkf, qf, kf);
    // 5. sliding window attention -> cat_bf[:,1024:]
    window_kernel<<<RTOT * NH, 64, 0, stream>>>(q, k, v, cat_bf);
    // 6. linear attention (MFMA) -> cat_bf[:,:1024]
    lin_mfma_kernel<<<dim3(TT / 64, BB * NH), 256, 0, stream>>>(qf, kf, v, cat_bf);
    // 7. output projection + residual (bf16 MFMA)
    gemm_out_mfma<<<dim3(8, 32), 256, 0, stream>>>(cat_bf, WoT, x, out);
}

// Round 3
// 337.478 us; speedup vs baseline: 4.7293x; 1.7536x over previous
//
#include <hip/hip_runtime.h>
#include <math.h>

// Problem constants
#define BB 2
#define TT 2048
#define DM 1024
#define NH 16
#define HD 64
#define FEAT 16
#define WIN 64
#define RTOT (BB*TT)        // 4096 rows

typedef __bf16 bf16x8 __attribute__((ext_vector_type(8)));
typedef float  f32x4  __attribute__((ext_vector_type(4)));
typedef float  f32x16 __attribute__((ext_vector_type(16)));

__device__ __forceinline__ unsigned short f2bf(float f) {
    union { float f; unsigned u; } v; v.f = f;
    unsigned r = v.u + 0x7FFFu + ((v.u >> 16) & 1u);   // RNE
    return (unsigned short)(r >> 16);
}
__device__ __forceinline__ float bf2f(unsigned short u) {
    union { unsigned u; float f; } v; v.u = ((unsigned)u) << 16; return v.f;
}

__device__ __forceinline__ void gl2lds16(const void* g, void* l) {
    __builtin_amdgcn_global_load_lds(
        (const __attribute__((address_space(1))) void*)g,
        (__attribute__((address_space(3))) void*)l, 16, 0, 0);
}

// ---------------------------------------------------------------------------
// Kernel 1: RMSNorm -> bf16 output
// ---------------------------------------------------------------------------
__global__ __launch_bounds__(256) void rmsnorm_kernel(const float* __restrict__ x,
                                                      const float* __restrict__ w,
                                                      unsigned short* __restrict__ h_bf) {
    int row = blockIdx.x;
    int tid = threadIdx.x;
    const float4* xr = (const float4*)(x + (size_t)row * DM);
    float4 xv = xr[tid];
    float ss = xv.x*xv.x + xv.y*xv.y + xv.z*xv.z + xv.w*xv.w;
    #pragma unroll
    for (int off = 32; off > 0; off >>= 1) ss += __shfl_down(ss, off, 64);
    __shared__ float red[4];
    if ((tid & 63) == 0) red[tid >> 6] = ss;
    __syncthreads();
    float tot = red[0] + red[1] + red[2] + red[3];
    float scale = rsqrtf(tot * (1.0f / DM) + 1e-6f);
    float4 wv = ((const float4*)w)[tid];
    ushort4 o;
    o.x = f2bf(xv.x * scale * wv.x);
    o.y = f2bf(xv.y * scale * wv.y);
    o.z = f2bf(xv.z * scale * wv.z);
    o.w = f2bf(xv.w * scale * wv.w);
    *(ushort4*)&h_bf[(size_t)row * DM + tid * 4] = o;
}

// ---------------------------------------------------------------------------
// Kernel 2: transpose + fp32->bf16 convert.  W [K][N] fp32 -> WT [N][K] bf16
// ---------------------------------------------------------------------------
__global__ __launch_bounds__(256) void transpose_bf16_kernel(const float* __restrict__ W,
                                                             unsigned short* __restrict__ WT,
                                                             int K, int N) {
    __shared__ float tile[64][65];
    int k0 = blockIdx.y * 64, n0 = blockIdx.x * 64;
    int t = threadIdx.x;
    int r = t >> 4, c4 = (t & 15) * 4;
    #pragma unroll
    for (int i = 0; i < 4; i++) {
        float4 vv = *(const float4*)&W[(size_t)(k0 + r + i*16) * N + n0 + c4];
        tile[r + i*16][c4 + 0] = vv.x;
        tile[r + i*16][c4 + 1] = vv.y;
        tile[r + i*16][c4 + 2] = vv.z;
        tile[r + i*16][c4 + 3] = vv.w;
    }
    __syncthreads();
    int rn = t >> 2, kq = (t & 3) * 16;
    unsigned short u[16];
    #pragma unroll
    for (int i = 0; i < 16; i++) u[i] = f2bf(tile[kq + i][rn]);
    size_t base = (size_t)(n0 + rn) * K + k0 + kq;
    *(uint4*)&WT[base]     = *(uint4*)&u[0];
    *(uint4*)&WT[base + 8] = *(uint4*)&u[8];
}

// ---------------------------------------------------------------------------
// bf16 MFMA GEMM core: 128x128 tile, BK=32, global_load_lds + XOR k-chunk perm.
// Output: fp32 (Cf, optional +resid) or bf16 (Cb).
// ---------------------------------------------------------------------------
__device__ __forceinline__ void gemm_core(const unsigned short* __restrict__ A,
                                          const unsigned short* __restrict__ BT,
                                          float* __restrict__ Cf,
                                          unsigned short* __restrict__ Cb,
                                          const float* __restrict__ resid,
                                          int K) {
    const int N = 1024;
    __shared__ __align__(16) unsigned short As[128 * 32];
    __shared__ __align__(16) unsigned short Bs[128 * 32];
    int tid = threadIdx.x;
    int lane = tid & 63;
    int w = tid >> 6;
    int wm = (w >> 1) * 64, wn = (w & 1) * 64;
    int m0 = blockIdx.y * 128, n0 = blockIdx.x * 128;
    int hi = lane >> 4;

    f32x4 acc[4][4];
    #pragma unroll
    for (int i = 0; i < 4; i++)
        #pragma unroll
        for (int j = 0; j < 4; j++)
            acc[i][j] = (f32x4){0.f, 0.f, 0.f, 0.f};

    for (int kt = 0; kt < K; kt += 32) {
        __syncthreads();
        #pragma unroll
        for (int half = 0; half < 2; half++) {
            int c = tid + half * 256;
            int row = c >> 2, pos = c & 3;
            int kh = (pos - (row >> 1)) & 3;
            gl2lds16(A  + (size_t)(m0 + row) * K + kt + kh * 8, &As[c * 8]);
            gl2lds16(BT + (size_t)(n0 + row) * K + kt + kh * 8, &Bs[c * 8]);
        }
        __syncthreads();
        bf16x8 af[4], bfr[4];
        #pragma unroll
        for (int i = 0; i < 4; i++) {
            int m = wm + i * 16 + (lane & 15);
            af[i]  = *(const bf16x8*)&As[m * 32 + (((hi + (m >> 1)) & 3) * 8)];
            int n = wn + i * 16 + (lane & 15);
            bfr[i] = *(const bf16x8*)&Bs[n * 32 + (((hi + (n >> 1)) & 3) * 8)];
        }
        #pragma unroll
        for (int i = 0; i < 4; i++)
            #pragma unroll
            for (int j = 0; j < 4; j++)
                acc[i][j] = __builtin_amdgcn_mfma_f32_16x16x32_bf16(af[i], bfr[j], acc[i][j], 0, 0, 0);
    }
    #pragma unroll
    for (int i = 0; i < 4; i++) {
        #pragma unroll
        for (int j = 0; j < 4; j++) {
            int col = n0 + wn + j * 16 + (lane & 15);
            #pragma unroll
            for (int r = 0; r < 4; r++) {
                int row = m0 + wm + i * 16 + hi * 4 + r;
                float vv = acc[i][j][r];
                if (Cb) {
                    Cb[(size_t)row * N + col] = f2bf(vv);
                } else {
                    if (resid) vv += resid[(size_t)row * N + col];
                    Cf[(size_t)row * N + col] = vv;
                }
            }
        }
    }
}

__global__ __launch_bounds__(256) void gemm_qkv_mfma(const unsigned short* __restrict__ A,
                                                     const unsigned short* __restrict__ BT0,
                                                     const unsigned short* __restrict__ BT1,
                                                     const unsigned short* __restrict__ BT2,
                                                     unsigned short* __restrict__ C0,
                                                     unsigned short* __restrict__ C1,
                                                     unsigned short* __restrict__ C2) {
    const unsigned short* BT = (blockIdx.z == 0) ? BT0 : (blockIdx.z == 1) ? BT1 : BT2;
    unsigned short* C = (blockIdx.z == 0) ? C0 : (blockIdx.z == 1) ? C1 : C2;
    gemm_core(A, BT, nullptr, C, nullptr, 1024);
}

__global__ __launch_bounds__(256) void gemm_out_mfma(const unsigned short* __restrict__ A,
                                                     const unsigned short* __restrict__ BT,
                                                     const float* __restrict__ resid,
                                                     float* __restrict__ C) {
    gemm_core(A, BT, C, nullptr, resid, 2048);
}

// ---------------------------------------------------------------------------
// Kernel 3: feature projection (bf16 in, bf16 out)
// ---------------------------------------------------------------------------
__global__ __launch_bounds__(256) void feat_kernel(const unsigned short* __restrict__ qb,
                                                   const unsigned short* __restrict__ kb,
                                                   const float* __restrict__ Wqf,
                                                   const float* __restrict__ Wkf,
                                                   unsigned short* __restrict__ qf,
                                                   unsigned short* __restrict__ kf) {
    __shared__ float Wl[HD * FEAT];
    const unsigned short* src = blockIdx.z ? kb : qb;
    const float* Wm = blockIdx.z ? Wkf : Wqf;
    unsigned short* dst = blockIdx.z ? kf : qf;
    int tid = threadIdx.x;
    ((float4*)Wl)[tid] = ((const float4*)Wm)[tid];
    __syncthreads();
    int gid = blockIdx.x * 256 + tid;
    int f = gid & 15;
    int rowh = gid >> 4;
    const unsigned short* s = src + (size_t)rowh * HD;
    float acc = 0.f;
    #pragma unroll
    for (int d = 0; d < HD; d++) acc += bf2f(s[d]) * Wl[d * FEAT + f];
    dst[gid] = f2bf(acc);
}

// ---------------------------------------------------------------------------
// Kernel 4: sliding-window attention, single-shot MFMA flash tile.
// Block = (qtile of 64 queries, b*h). Keys staged: [t0-64, t0+63] (128).
// 4 waves, each owns 16 query rows. LDS octet-XOR swizzles keep ds_read_b128
// conflicts <=2-way (free).
// ---------------------------------------------------------------------------
__global__ __launch_bounds__(256) void win_mfma_kernel(const unsigned short* __restrict__ q_bf,
                                                       const unsigned short* __restrict__ k_bf,
                                                       const unsigned short* __restrict__ v_bf,
                                                       unsigned short* __restrict__ cat_bf) {
    int qtile = blockIdx.x;
    int bh = blockIdx.y;
    int h = bh & 15;
    int b = bh >> 4;
    int tid = threadIdx.x;
    int lane = tid & 63;
    int wv = tid >> 6;
    int qr0 = wv * 16;
    int t0 = qtile * 64;
    int k0 = t0 - 64;

    __shared__ __align__(16) unsigned short Qs[64 * 64];    // [qrow][dim], 8 octet slots/row
    __shared__ __align__(16) unsigned short Ks[128 * 64];   // [key][dim]
    __shared__ __align__(16) unsigned short Vt[64 * 128];   // [dim][key], 16 octets/row
    __shared__ __align__(16) unsigned short Pl[64 * 128];   // [qrow][key]

    // stage Q (octet at pos p holds global octet (p - row)&7)
    #pragma unroll
    for (int half = 0; half < 2; half++) {
        int slot = tid + half * 256;
        int row = slot >> 3, pos = slot & 7;
        int o = (pos - row) & 7;
        gl2lds16(q_bf + (size_t)(b * TT + t0 + row) * (NH * HD) + h * HD + o * 8,
                 &Qs[slot * 8]);
    }
    // stage K (zero-fill keys < 0)
    #pragma unroll
    for (int qd = 0; qd < 4; qd++) {
        int slot = tid + qd * 256;
        int row = slot >> 3, pos = slot & 7;
        int o = (pos - row) & 7;
        int kg = k0 + row;
        if (kg >= 0) {
            gl2lds16(k_bf + (size_t)(b * TT + kg) * (NH * HD) + h * HD + o * 8,
                     &Ks[slot * 8]);
        } else {
            uint4 z = {0, 0, 0, 0};
            *(uint4*)&Ks[slot * 8] = z;
        }
    }
    // stage V^T (transpose; zero-fill keys < 0). thread: key kk, dim-half dh.
    {
        int kk = tid & 127;
        int dh = tid >> 7;
        int kg = k0 + kk;
        unsigned short tmp[32];
        if (kg >= 0) {
            size_t base = (size_t)(b * TT + kg) * (NH * HD) + h * HD + dh * 32;
            *(uint4*)&tmp[0]  = *(const uint4*)&v_bf[base];
            *(uint4*)&tmp[8]  = *(const uint4*)&v_bf[base + 8];
            *(uint4*)&tmp[16] = *(const uint4*)&v_bf[base + 16];
            *(uint4*)&tmp[24] = *(const uint4*)&v_bf[base + 24];
        } else {
            #pragma unroll
            for (int d = 0; d < 32; d++) tmp[d] = 0;
        }
        int o = kk >> 3, klow = kk & 7;
        #pragma unroll
        for (int d = 0; d < 32; d++) {
            int dim = dh * 32 + d;
            Vt[dim * 128 + ((o + dim) & 15) * 8 + klow] = tmp[d];
        }
    }
    __syncthreads();

    // ---- scores: S[16 qrows][128 keys] per wave
    int hi = lane >> 4;
    int lan15 = lane & 15;
    f32x4 sc[8];
    #pragma unroll
    for (int nt = 0; nt < 8; nt++) sc[nt] = (f32x4){0.f, 0.f, 0.f, 0.f};
    #pragma unroll
    for (int ks = 0; ks < 2; ks++) {
        int m = qr0 + lan15;
        int oA = ks * 4 + hi;
        bf16x8 a = *(const bf16x8*)&Qs[m * 64 + ((oA + m) & 7) * 8];
        #pragma unroll
        for (int nt = 0; nt < 8; nt++) {
            int n = nt * 16 + lan15;
            bf16x8 bb = *(const bf16x8*)&Ks[n * 64 + ((oA + n) & 7) * 8];
            sc[nt] = __builtin_amdgcn_mfma_f32_16x16x32_bf16(a, bb, sc[nt], 0, 0, 0);
        }
    }

    // ---- softmax over 128 cols (mask: s>=0, s<=t, s>=t-64)
    float lrow[4];
    #pragma unroll
    for (int r = 0; r < 4; r++) {
        int tq = t0 + qr0 + hi * 4 + r;
        float mx = -1e30f;
        #pragma unroll
        for (int nt = 0; nt < 8; nt++) {
            int s = k0 + nt * 16 + lan15;
            bool ok = (s >= 0) && (s <= tq) && (s >= tq - WIN);
            float vv = ok ? sc[nt][r] * 0.125f : -1e30f;
            sc[nt][r] = vv;
            mx = fmaxf(mx, vv);
        }
        #pragma unroll
        for (int off = 1; off < 16; off <<= 1) mx = fmaxf(mx, __shfl_xor(mx, off, 64));
        float ls = 0.f;
        #pragma unroll
        for (int nt = 0; nt < 8; nt++) {
            float e = __expf(sc[nt][r] - mx);
            sc[nt][r] = e;
            ls += e;
        }
        #pragma unroll
        for (int off = 1; off < 16; off <<= 1) ls += __shfl_xor(ls, off, 64);
        lrow[r] = ls;
    }

    // ---- write P (bf16) to LDS in swizzled [row][key] layout
    #pragma unroll
    for (int nt = 0; nt < 8; nt++) {
        #pragma unroll
        for (int r = 0; r < 4; r++) {
            int row = qr0 + hi * 4 + r;
            int col = nt * 16 + lan15;
            Pl[row * 128 + (((col >> 3) + row) & 15) * 8 + (col & 7)] = f2bf(sc[nt][r]);
        }
    }
    __syncthreads();

    // ---- PV: y[16 qrows][64 dims]
    f32x4 y[4];
    #pragma unroll
    for (int nt = 0; nt < 4; nt++) y[nt] = (f32x4){0.f, 0.f, 0.f, 0.f};
    #pragma unroll
    for (int ks = 0; ks < 4; ks++) {
        int m = qr0 + lan15;
        int oA = ks * 4 + hi;
        bf16x8 a = *(const bf16x8*)&Pl[m * 128 + ((oA + m) & 15) * 8];
        #pragma unroll
        for (int nt = 0; nt < 4; nt++) {
            int n = nt * 16 + lan15;
            bf16x8 bb = *(const bf16x8*)&Vt[n * 128 + ((oA + n) & 15) * 8];
            y[nt] = __builtin_amdgcn_mfma_f32_16x16x32_bf16(a, bb, y[nt], 0, 0, 0);
        }
    }

    // ---- epilogue: divide by softmax denom, write bf16 into cat[:,1024:]
    #pragma unroll
    for (int nt = 0; nt < 4; nt++) {
        #pragma unroll
        for (int r = 0; r < 4; r++) {
            int row = qr0 + hi * 4 + r;
            int dim = nt * 16 + lan15;
            cat_bf[(size_t)(b * TT + t0 + row) * (2 * DM) + DM + h * HD + dim] =
                f2bf(y[nt][r] / lrow[r]);
        }
    }
}

// ---------------------------------------------------------------------------
// Kernel 5: linear attention via exact identity, MFMA 32x32x16 flash tiles.
//   phi(u).phi(w) = (1 + u.w/2)^2 ; z accumulated via MFMA against ones.
// ---------------------------------------------------------------------------
__global__ __launch_bounds__(256) void lin_mfma_kernel(const unsigned short* __restrict__ qf,
                                                       const unsigned short* __restrict__ kf,
                                                       const unsigned short* __restrict__ v_bf,
                                                       unsigned short* __restrict__ cat_bf) {
    int qtile = 31 - blockIdx.x;      // heavy blocks dispatch first
    int bh = blockIdx.y;
    int h = bh & 15;
    int b = bh >> 4;
    int tid = threadIdx.x;
    int lane = tid & 63;
    int w = tid >> 6;
    int m0 = (w >> 1) * 32;
    int n0 = (w & 1) * 32;
    int hi = lane >> 5;

    __shared__ __align__(16) unsigned short Qf_l[64 * 16];
    __shared__ __align__(16) unsigned short Kf_l[64 * 16];
    __shared__ __align__(16) unsigned short Vt_l[64 * 72];
    __shared__ __align__(16) unsigned short S_l[64 * 72];

    {   // stage Qf tile (64x16) bf16 direct
        int r = tid >> 2, f = (tid & 3) * 4;
        *(ushort4*)&Qf_l[r * 16 + f] =
            *(const ushort4*)&qf[((size_t)((b * TT + qtile * 64 + r) * NH + h)) * FEAT + f];
    }
    __syncthreads();
    bf16x8 aq = *(const bf16x8*)&Qf_l[(m0 + (lane & 31)) * 16 + hi * 8];

    f32x16 yacc, zacc, zro;
    #pragma unroll
    for (int i = 0; i < 16; i++) { yacc[i] = 0.f; zacc[i] = 0.f; zro[i] = 0.f; }
    union { unsigned short u[8]; bf16x8 v; } onesu;
    #pragma unroll
    for (int i = 0; i < 8; i++) onesu.u[i] = 0x3F80;
    bf16x8 ones8 = onesu.v;

    for (int st = 0; st <= qtile; st++) {
        __syncthreads();
        {   // stage Kf tile
            int r = tid >> 2, f = (tid & 3) * 4;
            *(ushort4*)&Kf_l[r * 16 + f] =
                *(const ushort4*)&kf[((size_t)((b * TT + st * 64 + r) * NH + h)) * FEAT + f];
        }
        {   // stage V^T tile (bf16 source)
            int p = tid & 31, dq = (tid >> 5) * 8;
            size_t base0 = ((size_t)((b * TT + st * 64 + 2 * p) * NH + h)) * HD + dq;
            size_t base1 = base0 + (size_t)NH * HD;
            unsigned short a[8], bq[8];
            *(uint4*)a  = *(const uint4*)&v_bf[base0];
            *(uint4*)bq = *(const uint4*)&v_bf[base1];
            #pragma unroll
            for (int d = 0; d < 8; d++) {
                ushort2 u; u.x = a[d]; u.y = bq[d];
                *(ushort2*)&Vt_l[(dq + d) * 72 + 2 * p] = u;
            }
        }
        __syncthreads();
        bf16x8 bk = *(const bf16x8*)&Kf_l[(n0 + (lane & 31)) * 16 + hi * 8];
        f32x16 sc = __builtin_amdgcn_mfma_f32_32x32x16_bf16(aq, bk, zro, 0, 0, 0);
        bool diag = (st == qtile);
        int colk = n0 + (lane & 31);
        #pragma unroll
        for (int r = 0; r < 16; r++) {
            int rowq = m0 + (r & 3) + 8 * (r >> 2) + 4 * hi;
            float s = 1.f + 0.5f * sc[r];
            s = s * s;
            if (diag && colk > rowq) s = 0.f;
            S_l[rowq * 72 + colk] = f2bf(s);
        }
        __syncthreads();
        #pragma unroll
        for (int kt = 0; kt < 4; kt++) {
            bf16x8 as = *(const bf16x8*)&S_l[(m0 + (lane & 31)) * 72 + kt * 16 + hi * 8];
            bf16x8 bv = *(const bf16x8*)&Vt_l[(n0 + (lane & 31)) * 72 + kt * 16 + hi * 8];
            yacc = __builtin_amdgcn_mfma_f32_32x32x16_bf16(as, bv, yacc, 0, 0, 0);
            zacc = __builtin_amdgcn_mfma_f32_32x32x16_bf16(as, ones8, zacc, 0, 0, 0);
        }
    }
    int dcol = n0 + (lane & 31);
    #pragma unroll
    for (int r = 0; r < 16; r++) {
        int rowq = m0 + (r & 3) + 8 * (r >> 2) + 4 * hi;
        cat_bf[((size_t)(b * TT + qtile * 64 + rowq)) * (2 * DM) + h * 64 + dcol] =
            f2bf(yacc[r] / (zacc[r] + 1e-6f));
    }
}

// ---------------------------------------------------------------------------
extern "C" void kernel_launch(void* const* d_in, const int* in_sizes, int n_in,
                              void* d_out, int out_size, void* d_ws, size_t ws_size,
                              hipStream_t stream) {
    const float* x      = (const float*)d_in[0];
    const float* norm_w = (const float*)d_in[1];
    const float* Wq     = (const float*)d_in[2];
    const float* Wk     = (const float*)d_in[3];
    const float* Wv     = (const float*)d_in[4];
    const float* Wqf    = (const float*)d_in[5];
    const float* Wkf    = (const float*)d_in[6];
    const float* Wout   = (const float*)d_in[7];
    float* out = (float*)d_out;

    char* p = (char*)d_ws;
    unsigned short* h_bf = (unsigned short*)p; p += (size_t)RTOT * DM * 2;       // 8 MB
    unsigned short* WqT  = (unsigned short*)p; p += (size_t)DM * DM * 2;         // 2 MB
    unsigned short* WkT  = (unsigned short*)p; p += (size_t)DM * DM * 2;
    unsigned short* WvT  = (unsigned short*)p; p += (size_t)DM * DM * 2;
    unsigned short* WoT  = (unsigned short*)p; p += (size_t)DM * 2 * DM * 2;     // 4 MB
    unsigned short* q_bf = (unsigned short*)p; p += (size_t)RTOT * DM * 2;       // 8 MB
    unsigned short* k_bf = (unsigned short*)p; p += (size_t)RTOT * DM * 2;
    unsigned short* v_bf = (unsigned short*)p; p += (size_t)RTOT * DM * 2;
    unsigned short* qf_bf = (unsigned short*)p; p += (size_t)RTOT * NH * FEAT * 2; // 2 MB
    unsigned short* kf_bf = (unsigned short*)p; p += (size_t)RTOT * NH * FEAT * 2;
    unsigned short* cat_bf = (unsigned short*)p; p += (size_t)RTOT * 2 * DM * 2;   // 16 MB

    rmsnorm_kernel<<<RTOT, 256, 0, stream>>>(x, norm_w, h_bf);
    transpose_bf16_kernel<<<dim3(16, 16), 256, 0, stream>>>(Wq, WqT, 1024, 1024);
    transpose_bf16_kernel<<<dim3(16, 16), 256, 0, stream>>>(Wk, WkT, 1024, 1024);
    transpose_bf16_kernel<<<dim3(16, 16), 256, 0, stream>>>(Wv, WvT, 1024, 1024);
    transpose_bf16_kernel<<<dim3(16, 32), 256, 0, stream>>>(Wout, WoT, 2048, 1024);
    gemm_qkv_mfma<<<dim3(8, 32, 3), 256, 0, stream>>>(h_bf, WqT, WkT, WvT, q_bf, k_bf, v_bf);
    feat_kernel<<<dim3((RTOT * NH * FEAT) / 256, 1, 2), 256, 0, stream>>>(q_bf, k_bf, Wqf, Wkf, qf_bf, kf_bf);
    win_mfma_kernel<<<dim3(TT / 64, BB * NH), 256, 0, stream>>>(q_bf, k_bf, v_bf, cat_bf);
    lin_mfma_kernel<<<dim3(TT / 64, BB * NH), 256, 0, stream>>>(qf_bf, kf_bf, v_bf, cat_bf);
    gemm_out_mfma<<<dim3(8, 32), 256, 0, stream>>>(cat_bf, WoT, x, out);
}

// Round 4
// 315.977 us; speedup vs baseline: 5.0511x; 1.0680x over previous
//
#include <hip/hip_runtime.h>
#include <math.h>

// Problem constants
#define BB 2
#define TT 2048
#define DM 1024
#define NH 16
#define HD 64
#define FEAT 16
#define WIN 64
#define RTOT (BB*TT)        // 4096 rows

typedef __bf16 bf16x8 __attribute__((ext_vector_type(8)));
typedef float  f32x4  __attribute__((ext_vector_type(4)));

__device__ __forceinline__ unsigned short f2bf(float f) {
    union { float f; unsigned u; } v; v.f = f;
    unsigned r = v.u + 0x7FFFu + ((v.u >> 16) & 1u);   // RNE
    return (unsigned short)(r >> 16);
}
__device__ __forceinline__ float bf2f(unsigned short u) {
    union { unsigned u; float f; } v; v.u = ((unsigned)u) << 16; return v.f;
}

__device__ __forceinline__ void gl2lds16(const void* g, void* l) {
    __builtin_amdgcn_global_load_lds(
        (const __attribute__((address_space(1))) void*)g,
        (__attribute__((address_space(3))) void*)l, 16, 0, 0);
}

// ---------------------------------------------------------------------------
// Kernel 1: RMSNorm -> bf16 output
// ---------------------------------------------------------------------------
__global__ __launch_bounds__(256) void rmsnorm_kernel(const float* __restrict__ x,
                                                      const float* __restrict__ w,
                                                      unsigned short* __restrict__ h_bf) {
    int row = blockIdx.x;
    int tid = threadIdx.x;
    const float4* xr = (const float4*)(x + (size_t)row * DM);
    float4 xv = xr[tid];
    float ss = xv.x*xv.x + xv.y*xv.y + xv.z*xv.z + xv.w*xv.w;
    #pragma unroll
    for (int off = 32; off > 0; off >>= 1) ss += __shfl_down(ss, off, 64);
    __shared__ float red[4];
    if ((tid & 63) == 0) red[tid >> 6] = ss;
    __syncthreads();
    float tot = red[0] + red[1] + red[2] + red[3];
    float scale = rsqrtf(tot * (1.0f / DM) + 1e-6f);
    float4 wv = ((const float4*)w)[tid];
    ushort4 o;
    o.x = f2bf(xv.x * scale * wv.x);
    o.y = f2bf(xv.y * scale * wv.y);
    o.z = f2bf(xv.z * scale * wv.z);
    o.w = f2bf(xv.w * scale * wv.w);
    *(ushort4*)&h_bf[(size_t)row * DM + tid * 4] = o;
}

// ---------------------------------------------------------------------------
// Kernel 2: transpose + fp32->bf16 convert.  W [K][N] fp32 -> WT [N][K] bf16
// ---------------------------------------------------------------------------
__global__ __launch_bounds__(256) void transpose_bf16_kernel(const float* __restrict__ W,
                                                             unsigned short* __restrict__ WT,
                                                             int K, int N) {
    __shared__ float tile[64][65];
    int k0 = blockIdx.y * 64, n0 = blockIdx.x * 64;
    int t = threadIdx.x;
    int r = t >> 4, c4 = (t & 15) * 4;
    #pragma unroll
    for (int i = 0; i < 4; i++) {
        float4 vv = *(const float4*)&W[(size_t)(k0 + r + i*16) * N + n0 + c4];
        tile[r + i*16][c4 + 0] = vv.x;
        tile[r + i*16][c4 + 1] = vv.y;
        tile[r + i*16][c4 + 2] = vv.z;
        tile[r + i*16][c4 + 3] = vv.w;
    }
    __syncthreads();
    int rn = t >> 2, kq = (t & 3) * 16;
    unsigned short u[16];
    #pragma unroll
    for (int i = 0; i < 16; i++) u[i] = f2bf(tile[kq + i][rn]);
    size_t base = (size_t)(n0 + rn) * K + k0 + kq;
    *(uint4*)&WT[base]     = *(uint4*)&u[0];
    *(uint4*)&WT[base + 8] = *(uint4*)&u[8];
}

// ---------------------------------------------------------------------------
// bf16 MFMA GEMM core: 128x128 tile, BK=32, global_load_lds + XOR k-chunk perm.
// ---------------------------------------------------------------------------
__device__ __forceinline__ void gemm_core(const unsigned short* __restrict__ A,
                                          const unsigned short* __restrict__ BT,
                                          float* __restrict__ Cf,
                                          unsigned short* __restrict__ Cb,
                                          const float* __restrict__ resid,
                                          int K) {
    const int N = 1024;
    __shared__ __align__(16) unsigned short As[128 * 32];
    __shared__ __align__(16) unsigned short Bs[128 * 32];
    int tid = threadIdx.x;
    int lane = tid & 63;
    int w = tid >> 6;
    int wm = (w >> 1) * 64, wn = (w & 1) * 64;
    int m0 = blockIdx.y * 128, n0 = blockIdx.x * 128;
    int hi = lane >> 4;

    f32x4 acc[4][4];
    #pragma unroll
    for (int i = 0; i < 4; i++)
        #pragma unroll
        for (int j = 0; j < 4; j++)
            acc[i][j] = (f32x4){0.f, 0.f, 0.f, 0.f};

    for (int kt = 0; kt < K; kt += 32) {
        __syncthreads();
        #pragma unroll
        for (int half = 0; half < 2; half++) {
            int c = tid + half * 256;
            int row = c >> 2, pos = c & 3;
            int kh = (pos - (row >> 1)) & 3;
            gl2lds16(A  + (size_t)(m0 + row) * K + kt + kh * 8, &As[c * 8]);
            gl2lds16(BT + (size_t)(n0 + row) * K + kt + kh * 8, &Bs[c * 8]);
        }
        __syncthreads();
        bf16x8 af[4], bfr[4];
        #pragma unroll
        for (int i = 0; i < 4; i++) {
            int m = wm + i * 16 + (lane & 15);
            af[i]  = *(const bf16x8*)&As[m * 32 + (((hi + (m >> 1)) & 3) * 8)];
            int n = wn + i * 16 + (lane & 15);
            bfr[i] = *(const bf16x8*)&Bs[n * 32 + (((hi + (n >> 1)) & 3) * 8)];
        }
        #pragma unroll
        for (int i = 0; i < 4; i++)
            #pragma unroll
            for (int j = 0; j < 4; j++)
                acc[i][j] = __builtin_amdgcn_mfma_f32_16x16x32_bf16(af[i], bfr[j], acc[i][j], 0, 0, 0);
    }
    #pragma unroll
    for (int i = 0; i < 4; i++) {
        #pragma unroll
        for (int j = 0; j < 4; j++) {
            int col = n0 + wn + j * 16 + (lane & 15);
            #pragma unroll
            for (int r = 0; r < 4; r++) {
                int row = m0 + wm + i * 16 + hi * 4 + r;
                float vv = acc[i][j][r];
                if (Cb) {
                    Cb[(size_t)row * N + col] = f2bf(vv);
                } else {
                    if (resid) vv += resid[(size_t)row * N + col];
                    Cf[(size_t)row * N + col] = vv;
                }
            }
        }
    }
}

__global__ __launch_bounds__(256) void gemm_qkv_mfma(const unsigned short* __restrict__ A,
                                                     const unsigned short* __restrict__ BT0,
                                                     const unsigned short* __restrict__ BT1,
                                                     const unsigned short* __restrict__ BT2,
                                                     unsigned short* __restrict__ C0,
                                                     unsigned short* __restrict__ C1,
                                                     unsigned short* __restrict__ C2) {
    const unsigned short* BT = (blockIdx.z == 0) ? BT0 : (blockIdx.z == 1) ? BT1 : BT2;
    unsigned short* C = (blockIdx.z == 0) ? C0 : (blockIdx.z == 1) ? C1 : C2;
    gemm_core(A, BT, nullptr, C, nullptr, 1024);
}

__global__ __launch_bounds__(256) void gemm_out_mfma(const unsigned short* __restrict__ A,
                                                     const unsigned short* __restrict__ BT,
                                                     const float* __restrict__ resid,
                                                     float* __restrict__ C) {
    gemm_core(A, BT, C, nullptr, resid, 2048);
}

// ---------------------------------------------------------------------------
// Kernel 3: feature projection (bf16 in, bf16 out)
// ---------------------------------------------------------------------------
__global__ __launch_bounds__(256) void feat_kernel(const unsigned short* __restrict__ qb,
                                                   const unsigned short* __restrict__ kb,
                                                   const float* __restrict__ Wqf,
                                                   const float* __restrict__ Wkf,
                                                   unsigned short* __restrict__ qf,
                                                   unsigned short* __restrict__ kf) {
    __shared__ float Wl[HD * FEAT];
    const unsigned short* src = blockIdx.z ? kb : qb;
    const float* Wm = blockIdx.z ? Wkf : Wqf;
    unsigned short* dst = blockIdx.z ? kf : qf;
    int tid = threadIdx.x;
    ((float4*)Wl)[tid] = ((const float4*)Wm)[tid];
    __syncthreads();
    int gid = blockIdx.x * 256 + tid;
    int f = gid & 15;
    int rowh = gid >> 4;
    const unsigned short* s = src + (size_t)rowh * HD;
    float acc = 0.f;
    #pragma unroll
    for (int d = 0; d < HD; d++) acc += bf2f(s[d]) * Wl[d * FEAT + f];
    dst[gid] = f2bf(acc);
}

// ---------------------------------------------------------------------------
// Kernel 4: sliding-window attention, single-shot MFMA flash tile.
// ---------------------------------------------------------------------------
__global__ __launch_bounds__(256) void win_mfma_kernel(const unsigned short* __restrict__ q_bf,
                                                       const unsigned short* __restrict__ k_bf,
                                                       const unsigned short* __restrict__ v_bf,
                                                       unsigned short* __restrict__ cat_bf) {
    int qtile = blockIdx.x;
    int bh = blockIdx.y;
    int h = bh & 15;
    int b = bh >> 4;
    int tid = threadIdx.x;
    int lane = tid & 63;
    int wv = tid >> 6;
    int qr0 = wv * 16;
    int t0 = qtile * 64;
    int k0 = t0 - 64;

    __shared__ __align__(16) unsigned short Qs[64 * 64];
    __shared__ __align__(16) unsigned short Ks[128 * 64];
    __shared__ __align__(16) unsigned short Vt[64 * 128];
    __shared__ __align__(16) unsigned short Pl[64 * 128];

    #pragma unroll
    for (int half = 0; half < 2; half++) {
        int slot = tid + half * 256;
        int row = slot >> 3, pos = slot & 7;
        int o = (pos - row) & 7;
        gl2lds16(q_bf + (size_t)(b * TT + t0 + row) * (NH * HD) + h * HD + o * 8,
                 &Qs[slot * 8]);
    }
    #pragma unroll
    for (int qd = 0; qd < 4; qd++) {
        int slot = tid + qd * 256;
        int row = slot >> 3, pos = slot & 7;
        int o = (pos - row) & 7;
        int kg = k0 + row;
        if (kg >= 0) {
            gl2lds16(k_bf + (size_t)(b * TT + kg) * (NH * HD) + h * HD + o * 8,
                     &Ks[slot * 8]);
        } else {
            uint4 z = {0, 0, 0, 0};
            *(uint4*)&Ks[slot * 8] = z;
        }
    }
    {
        int kk = tid & 127;
        int dh = tid >> 7;
        int kg = k0 + kk;
        unsigned short tmp[32];
        if (kg >= 0) {
            size_t base = (size_t)(b * TT + kg) * (NH * HD) + h * HD + dh * 32;
            *(uint4*)&tmp[0]  = *(const uint4*)&v_bf[base];
            *(uint4*)&tmp[8]  = *(const uint4*)&v_bf[base + 8];
            *(uint4*)&tmp[16] = *(const uint4*)&v_bf[base + 16];
            *(uint4*)&tmp[24] = *(const uint4*)&v_bf[base + 24];
        } else {
            #pragma unroll
            for (int d = 0; d < 32; d++) tmp[d] = 0;
        }
        int o = kk >> 3, klow = kk & 7;
        #pragma unroll
        for (int d = 0; d < 32; d++) {
            int dim = dh * 32 + d;
            Vt[dim * 128 + ((o + dim) & 15) * 8 + klow] = tmp[d];
        }
    }
    __syncthreads();

    int hi = lane >> 4;
    int lan15 = lane & 15;
    f32x4 sc[8];
    #pragma unroll
    for (int nt = 0; nt < 8; nt++) sc[nt] = (f32x4){0.f, 0.f, 0.f, 0.f};
    #pragma unroll
    for (int ks = 0; ks < 2; ks++) {
        int m = qr0 + lan15;
        int oA = ks * 4 + hi;
        bf16x8 a = *(const bf16x8*)&Qs[m * 64 + ((oA + m) & 7) * 8];
        #pragma unroll
        for (int nt = 0; nt < 8; nt++) {
            int n = nt * 16 + lan15;
            bf16x8 bb = *(const bf16x8*)&Ks[n * 64 + ((oA + n) & 7) * 8];
            sc[nt] = __builtin_amdgcn_mfma_f32_16x16x32_bf16(a, bb, sc[nt], 0, 0, 0);
        }
    }

    float lrow[4];
    #pragma unroll
    for (int r = 0; r < 4; r++) {
        int tq = t0 + qr0 + hi * 4 + r;
        float mx = -1e30f;
        #pragma unroll
        for (int nt = 0; nt < 8; nt++) {
            int s = k0 + nt * 16 + lan15;
            bool ok = (s >= 0) && (s <= tq) && (s >= tq - WIN);
            float vv = ok ? sc[nt][r] * 0.125f : -1e30f;
            sc[nt][r] = vv;
            mx = fmaxf(mx, vv);
        }
        #pragma unroll
        for (int off = 1; off < 16; off <<= 1) mx = fmaxf(mx, __shfl_xor(mx, off, 64));
        float ls = 0.f;
        #pragma unroll
        for (int nt = 0; nt < 8; nt++) {
            float e = __expf(sc[nt][r] - mx);
            sc[nt][r] = e;
            ls += e;
        }
        #pragma unroll
        for (int off = 1; off < 16; off <<= 1) ls += __shfl_xor(ls, off, 64);
        lrow[r] = ls;
    }

    #pragma unroll
    for (int nt = 0; nt < 8; nt++) {
        #pragma unroll
        for (int r = 0; r < 4; r++) {
            int row = qr0 + hi * 4 + r;
            int col = nt * 16 + lan15;
            Pl[row * 128 + (((col >> 3) + row) & 15) * 8 + (col & 7)] = f2bf(sc[nt][r]);
        }
    }
    __syncthreads();

    f32x4 y[4];
    #pragma unroll
    for (int nt = 0; nt < 4; nt++) y[nt] = (f32x4){0.f, 0.f, 0.f, 0.f};
    #pragma unroll
    for (int ks = 0; ks < 4; ks++) {
        int m = qr0 + lan15;
        int oA = ks * 4 + hi;
        bf16x8 a = *(const bf16x8*)&Pl[m * 128 + ((oA + m) & 15) * 8];
        #pragma unroll
        for (int nt = 0; nt < 4; nt++) {
            int n = nt * 16 + lan15;
            bf16x8 bb = *(const bf16x8*)&Vt[n * 128 + ((oA + n) & 15) * 8];
            y[nt] = __builtin_amdgcn_mfma_f32_16x16x32_bf16(a, bb, y[nt], 0, 0, 0);
        }
    }

    #pragma unroll
    for (int nt = 0; nt < 4; nt++) {
        #pragma unroll
        for (int r = 0; r < 4; r++) {
            int row = qr0 + hi * 4 + r;
            int dim = nt * 16 + lan15;
            cat_bf[(size_t)(b * TT + t0 + row) * (2 * DM) + DM + h * HD + dim] =
                f2bf(y[nt][r] / lrow[r]);
        }
    }
}

// ---------------------------------------------------------------------------
// Linear attention, phi-space chunked (CHUNK=64, PHI=153 padded to 160):
//   phi(x) = [1, x, x_i x_j * (0.5 if i==j else 1/sqrt2) for i<=j]
//   y_t = phi_q(t)ᵀ KV_prefix + intra-chunk (1+qf·kf/2)² V ;  z analogous.
// kvbuf layout: [chunk 32][bh 32][row 65][f 160] bf16; row 64 = Ksum.
// ---------------------------------------------------------------------------
#define PHI 160
#define NCH 32
#define KVROWS 65
#define CH_STRIDE ((size_t)32 * KVROWS * PHI)

// Phase B: per-chunk KV^T via MFMA.  grid (32 chunks, 32 bh)
__global__ __launch_bounds__(256) void lin_kv_kernel(const unsigned short* __restrict__ kf,
                                                     const unsigned short* __restrict__ v_bf,
                                                     unsigned short* __restrict__ kvbuf) {
    int c = blockIdx.x, bh = blockIdx.y;
    int h = bh & 15, b = bh >> 4;
    int tid = threadIdx.x, lane = tid & 63, w = tid >> 6;
    int hi = lane >> 4, l15 = lane & 15;

    __shared__ unsigned short kf_l[64 * 16];
    __shared__ __align__(16) unsigned short PhiT[192 * 66];  // [f][token]
    __shared__ __align__(16) unsigned short Vt[80 * 66];     // [d|ones][token]
    __shared__ int iu[136], ju[136];
    __shared__ float sclut[136];

    if (tid < 136) {
        int qq = tid, i = 0;
        while (qq >= 16 - i) { qq -= 16 - i; i++; }
        iu[tid] = i; ju[tid] = i + qq;
        sclut[tid] = (qq == 0) ? 0.5f : 0.70710678118654752f;
    }
    {   // stage kf (64x16)
        int r = tid >> 2, f4 = (tid & 3) * 4;
        *(ushort4*)&kf_l[r * 16 + f4] =
            *(const ushort4*)&kf[((size_t)((b * TT + c * 64 + r) * NH + h)) * FEAT + f4];
    }
    {   // stage V^T + ones rows 64..79
        int p = tid & 31, dq = (tid >> 5) * 8;
        size_t base0 = ((size_t)(b * TT + c * 64 + 2 * p)) * DM + h * HD + dq;
        unsigned short a[8], bq[8];
        *(uint4*)a  = *(const uint4*)&v_bf[base0];
        *(uint4*)bq = *(const uint4*)&v_bf[base0 + DM];
        #pragma unroll
        for (int d = 0; d < 8; d++) {
            ushort2 u; u.x = a[d]; u.y = bq[d];
            *(ushort2*)&Vt[(dq + d) * 66 + 2 * p] = u;
        }
        #pragma unroll
        for (int i = 0; i < 4; i++) {
            int e = tid + i * 256;
            Vt[(64 + (e >> 6)) * 66 + (e & 63)] = 0x3F80;  // 1.0 bf16
        }
    }
    __syncthreads();
    {   // build PhiT[192][64] (rows >=160 zero)
        int s = tid & 63, fb = tid >> 6;
        float xr[16];
        #pragma unroll
        for (int i = 0; i < 16; i++) xr[i] = bf2f(kf_l[s * 16 + i]);
        for (int it = 0; it < 48; it++) {
            int f = fb + it * 4;
            float val;
            if (f == 0) val = 1.f;
            else if (f < 17) val = xr[f - 1];
            else if (f < 153) { int qq = f - 17; val = xr[iu[qq]] * xr[ju[qq]] * sclut[qq]; }
            else val = 0.f;
            PhiT[f * 66 + s] = f2bf(val);
        }
    }
    __syncthreads();
    // MFMA: M=80 (Vt rows), N-tiles 3w..3w+2 of 192, K=64
    f32x4 acc[5][3];
    #pragma unroll
    for (int m = 0; m < 5; m++)
        #pragma unroll
        for (int j = 0; j < 3; j++) acc[m][j] = (f32x4){0.f, 0.f, 0.f, 0.f};
    #pragma unroll
    for (int ks = 0; ks < 2; ks++) {
        bf16x8 bfrag[3];
        #pragma unroll
        for (int j = 0; j < 3; j++)
            bfrag[j] = *(const bf16x8*)&PhiT[((3 * w + j) * 16 + l15) * 66 + ks * 32 + hi * 8];
        #pragma unroll
        for (int m = 0; m < 5; m++) {
            bf16x8 afrag = *(const bf16x8*)&Vt[(m * 16 + l15) * 66 + ks * 32 + hi * 8];
            #pragma unroll
            for (int j = 0; j < 3; j++)
                acc[m][j] = __builtin_amdgcn_mfma_f32_16x16x32_bf16(afrag, bfrag[j], acc[m][j], 0, 0, 0);
        }
    }
    // epilogue: rows 0..64 (64 dims + Ksum), cols f<160
    size_t obase = ((size_t)c * 32 + bh) * (KVROWS * PHI);
    #pragma unroll
    for (int m = 0; m < 5; m++) {
        #pragma unroll
        for (int j = 0; j < 3; j++) {
            int f = (3 * w + j) * 16 + l15;
            if (f >= PHI) continue;
            #pragma unroll
            for (int r = 0; r < 4; r++) {
                int row = m * 16 + hi * 4 + r;
                if (row >= KVROWS) continue;
                kvbuf[obase + row * PHI + f] = f2bf(acc[m][j][r]);
            }
        }
    }
}

// Phase C: in-place exclusive prefix over chunks. grid (41, 32 bh)
__global__ __launch_bounds__(256) void lin_scan_kernel(unsigned short* __restrict__ kvbuf) {
    int e = blockIdx.x * 256 + threadIdx.x;
    int bh = blockIdx.y;
    if (e >= KVROWS * PHI) return;
    float acc = 0.f;
    size_t off = (size_t)bh * (KVROWS * PHI) + e;
    for (int c = 0; c < NCH; c++) {
        float vv = bf2f(kvbuf[off]);
        kvbuf[off] = f2bf(acc);
        acc += vv;
        off += CH_STRIDE;
    }
}

// Phase D: outputs. grid (32 chunks, 32 bh). Wave w owns token rows w*16..+15.
__global__ __launch_bounds__(256) void lin_out_kernel(const unsigned short* __restrict__ qf,
                                                      const unsigned short* __restrict__ kf,
                                                      const unsigned short* __restrict__ v_bf,
                                                      const unsigned short* __restrict__ kvbuf,
                                                      unsigned short* __restrict__ cat_bf) {
    int c = blockIdx.x, bh = blockIdx.y;
    int h = bh & 15, b = bh >> 4;
    int tid = threadIdx.x, lane = tid & 63, w = tid >> 6;
    int hi = lane >> 4, l15 = lane & 15;

    __shared__ __align__(16) unsigned short kf_lb[64 * 34];   // cols 16..31 zero
    __shared__ __align__(16) unsigned short KVS_l[80 * 162];  // rows 65..79 zero
    __shared__ __align__(16) unsigned short Vt[80 * 66];      // + ones rows
    __shared__ __align__(16) unsigned short P_l[64 * 66];
    __shared__ int iu[136], ju[136];
    __shared__ float sclut[136];

    if (tid < 136) {
        int qq = tid, i = 0;
        while (qq >= 16 - i) { qq -= 16 - i; i++; }
        iu[tid] = i; ju[tid] = i + qq;
        sclut[tid] = (qq == 0) ? 0.5f : 0.70710678118654752f;
    }
    {   // stage kf with zero pad
        int r = tid >> 2, f4 = (tid & 3) * 4;
        *(ushort4*)&kf_lb[r * 34 + f4] =
            *(const ushort4*)&kf[((size_t)((b * TT + c * 64 + r) * NH + h)) * FEAT + f4];
        ushort4 z4 = {0, 0, 0, 0};
        *(ushort4*)&kf_lb[r * 34 + 16 + f4] = z4;
    }
    {   // stage V^T + ones rows
        int p = tid & 31, dq = (tid >> 5) * 8;
        size_t base0 = ((size_t)(b * TT + c * 64 + 2 * p)) * DM + h * HD + dq;
        unsigned short a[8], bq[8];
        *(uint4*)a  = *(const uint4*)&v_bf[base0];
        *(uint4*)bq = *(const uint4*)&v_bf[base0 + DM];
        #pragma unroll
        for (int d = 0; d < 8; d++) {
            ushort2 u; u.x = a[d]; u.y = bq[d];
            *(ushort2*)&Vt[(dq + d) * 66 + 2 * p] = u;
        }
        #pragma unroll
        for (int i = 0; i < 4; i++) {
            int e = tid + i * 256;
            Vt[(64 + (e >> 6)) * 66 + (e & 63)] = 0x3F80;
        }
    }
    {   // stage KVS rows 0..64 (ushort4 granular), zero rows 65..79
        size_t gbase = ((size_t)c * 32 + bh) * (KVROWS * PHI);
        #pragma unroll
        for (int i = 0; i < 11; i++) {
            int e4 = tid + i * 256;
            if (e4 < KVROWS * 40) {
                int r = e4 / 40, f4 = (e4 % 40) * 4;
                *(ushort4*)&KVS_l[r * 162 + f4] =
                    *(const ushort4*)&kvbuf[gbase + r * PHI + f4];
            }
        }
        #pragma unroll
        for (int i = 0; i < 3; i++) {
            int e4 = tid + i * 256;
            if (e4 < 15 * 40) {
                int r = 65 + e4 / 40, f4 = (e4 % 40) * 4;
                ushort4 z4 = {0, 0, 0, 0};
                *(ushort4*)&KVS_l[r * 162 + f4] = z4;
            }
        }
    }
    // per-lane qf row (token fixed for all A-frags of this wave)
    int t_m = w * 16 + l15;
    float xr[16];
    {
        unsigned short qr[16];
        size_t qb = ((size_t)((b * TT + c * 64 + t_m) * NH + h)) * FEAT;
        *(ushort4*)&qr[0]  = *(const ushort4*)&qf[qb];
        *(ushort4*)&qr[4]  = *(const ushort4*)&qf[qb + 4];
        *(ushort4*)&qr[8]  = *(const ushort4*)&qf[qb + 8];
        *(ushort4*)&qr[12] = *(const ushort4*)&qf[qb + 12];
        #pragma unroll
        for (int i = 0; i < 16; i++) xr[i] = bf2f(qr[i]);
    }
    __syncthreads();

    f32x4 acc[5];
    #pragma unroll
    for (int n = 0; n < 5; n++) acc[n] = (f32x4){0.f, 0.f, 0.f, 0.f};

    // GEMM1: Phi_q (on the fly) x KVS
    #pragma unroll
    for (int ks = 0; ks < 5; ks++) {
        union { unsigned short u[8]; bf16x8 v; } af;
        int f0 = ks * 32 + hi * 8;
        #pragma unroll
        for (int j = 0; j < 8; j++) {
            int f = f0 + j;
            float val;
            if (f == 0) val = 1.f;
            else if (f < 17) val = xr[f - 1];
            else { int qq = f - 17; val = xr[iu[qq]] * xr[ju[qq]] * sclut[qq]; }
            af.u[j] = f2bf(val);
        }
        #pragma unroll
        for (int n = 0; n < 5; n++) {
            bf16x8 bb = *(const bf16x8*)&KVS_l[(n * 16 + l15) * 162 + ks * 32 + hi * 8];
            acc[n] = __builtin_amdgcn_mfma_f32_16x16x32_bf16(af.v, bb, acc[n], 0, 0, 0);
        }
    }

    // intra-chunk scores: S = (1 + qf.kf/2)^2, causal (diag included)
    {
        union { unsigned short u[8]; bf16x8 v; } aq;
        int f0 = hi * 8;
        #pragma unroll
        for (int j = 0; j < 8; j++) {
            int f = f0 + j;
            aq.u[j] = (f < 16) ? f2bf(xr[f]) : (unsigned short)0;
        }
        #pragma unroll
        for (int n = 0; n < 4; n++) {
            bf16x8 bk = *(const bf16x8*)&kf_lb[(n * 16 + l15) * 34 + hi * 8];
            f32x4 zv = {0.f, 0.f, 0.f, 0.f};
            f32x4 sc = __builtin_amdgcn_mfma_f32_16x16x32_bf16(aq.v, bk, zv, 0, 0, 0);
            int sl = n * 16 + l15;
            #pragma unroll
            for (int r = 0; r < 4; r++) {
                int rl = w * 16 + hi * 4 + r;
                float sv = 1.f + 0.5f * sc[r];
                sv = sv * sv;
                if (sl > rl) sv = 0.f;
                P_l[rl * 66 + sl] = f2bf(sv);
            }
        }
    }
    __syncthreads();

    // GEMM2: P x Vt (accumulates y into cols 0..63, z into cols 64..79)
    #pragma unroll
    for (int ks = 0; ks < 2; ks++) {
        bf16x8 a = *(const bf16x8*)&P_l[(w * 16 + l15) * 66 + ks * 32 + hi * 8];
        #pragma unroll
        for (int n = 0; n < 5; n++) {
            bf16x8 bb = *(const bf16x8*)&Vt[(n * 16 + l15) * 66 + ks * 32 + hi * 8];
            acc[n] = __builtin_amdgcn_mfma_f32_16x16x32_bf16(a, bb, acc[n], 0, 0, 0);
        }
    }

    // epilogue: z lives in col 64 (lane l15==0 of acc[4]); broadcast per row
    #pragma unroll
    for (int r = 0; r < 4; r++) {
        float zz = __shfl(acc[4][r], (lane & 48), 64);
        int token = c * 64 + w * 16 + hi * 4 + r;
        #pragma unroll
        for (int n = 0; n < 4; n++) {
            int d = n * 16 + l15;
            cat_bf[((size_t)(b * TT + token)) * (2 * DM) + h * HD + d] =
                f2bf(acc[n][r] / (zz + 1e-6f));
        }
    }
}

// ---------------------------------------------------------------------------
extern "C" void kernel_launch(void* const* d_in, const int* in_sizes, int n_in,
                              void* d_out, int out_size, void* d_ws, size_t ws_size,
                              hipStream_t stream) {
    const float* x      = (const float*)d_in[0];
    const float* norm_w = (const float*)d_in[1];
    const float* Wq     = (const float*)d_in[2];
    const float* Wk     = (const float*)d_in[3];
    const float* Wv     = (const float*)d_in[4];
    const float* Wqf    = (const float*)d_in[5];
    const float* Wkf    = (const float*)d_in[6];
    const float* Wout   = (const float*)d_in[7];
    float* out = (float*)d_out;

    char* p = (char*)d_ws;
    unsigned short* h_bf = (unsigned short*)p; p += (size_t)RTOT * DM * 2;       // 8 MB
    unsigned short* WqT  = (unsigned short*)p; p += (size_t)DM * DM * 2;         // 2 MB
    unsigned short* WkT  = (unsigned short*)p; p += (size_t)DM * DM * 2;
    unsigned short* WvT  = (unsigned short*)p; p += (size_t)DM * DM * 2;
    unsigned short* WoT  = (unsigned short*)p; p += (size_t)DM * 2 * DM * 2;     // 4 MB
    unsigned short* q_bf = (unsigned short*)p; p += (size_t)RTOT * DM * 2;       // 8 MB
    unsigned short* k_bf = (unsigned short*)p; p += (size_t)RTOT * DM * 2;
    unsigned short* v_bf = (unsigned short*)p; p += (size_t)RTOT * DM * 2;
    unsigned short* qf_bf = (unsigned short*)p; p += (size_t)RTOT * NH * FEAT * 2; // 2 MB
    unsigned short* kf_bf = (unsigned short*)p; p += (size_t)RTOT * NH * FEAT * 2;
    unsigned short* cat_bf = (unsigned short*)p; p += (size_t)RTOT * 2 * DM * 2;   // 16 MB
    unsigned short* kvbuf  = (unsigned short*)p; p += (size_t)NCH * 32 * KVROWS * PHI * 2; // 21.3 MB

    rmsnorm_kernel<<<RTOT, 256, 0, stream>>>(x, norm_w, h_bf);
    transpose_bf16_kernel<<<dim3(16, 16), 256, 0, stream>>>(Wq, WqT, 1024, 1024);
    transpose_bf16_kernel<<<dim3(16, 16), 256, 0, stream>>>(Wk, WkT, 1024, 1024);
    transpose_bf16_kernel<<<dim3(16, 16), 256, 0, stream>>>(Wv, WvT, 1024, 1024);
    transpose_bf16_kernel<<<dim3(16, 32), 256, 0, stream>>>(Wout, WoT, 2048, 1024);
    gemm_qkv_mfma<<<dim3(8, 32, 3), 256, 0, stream>>>(h_bf, WqT, WkT, WvT, q_bf, k_bf, v_bf);
    feat_kernel<<<dim3((RTOT * NH * FEAT) / 256, 1, 2), 256, 0, stream>>>(q_bf, k_bf, Wqf, Wkf, qf_bf, kf_bf);
    win_mfma_kernel<<<dim3(TT / 64, BB * NH), 256, 0, stream>>>(q_bf, k_bf, v_bf, cat_bf);
    lin_kv_kernel<<<dim3(NCH, BB * NH), 256, 0, stream>>>(kf_bf, v_bf, kvbuf);
    lin_scan_kernel<<<dim3((KVROWS * PHI + 255) / 256, BB * NH), 256, 0, stream>>>(kvbuf);
    lin_out_kernel<<<dim3(NCH, BB * NH), 256, 0, stream>>>(qf_bf, kf_bf, v_bf, kvbuf, cat_bf);
    gemm_out_mfma<<<dim3(8, 32), 256, 0, stream>>>(cat_bf, WoT, x, out);
}

// Round 5
// 282.812 us; speedup vs baseline: 5.6435x; 1.1173x over previous
//
#include <hip/hip_runtime.h>
#include <math.h>

// Problem constants
#define BB 2
#define TT 2048
#define DM 1024
#define NH 16
#define HD 64
#define FEAT 16
#define WIN 64
#define RTOT (BB*TT)        // 4096 rows

typedef __bf16 bf16x8 __attribute__((ext_vector_type(8)));
typedef float  f32x4  __attribute__((ext_vector_type(4)));

__device__ __forceinline__ unsigned short f2bf(float f) {
    union { float f; unsigned u; } v; v.f = f;
    unsigned r = v.u + 0x7FFFu + ((v.u >> 16) & 1u);   // RNE
    return (unsigned short)(r >> 16);
}
__device__ __forceinline__ float bf2f(unsigned short u) {
    union { unsigned u; float f; } v; v.u = ((unsigned)u) << 16; return v.f;
}

__device__ __forceinline__ void gl2lds16(const void* g, void* l) {
    __builtin_amdgcn_global_load_lds(
        (const __attribute__((address_space(1))) void*)g,
        (__attribute__((address_space(3))) void*)l, 16, 0, 0);
}

// ---------------------------------------------------------------------------
// Kernel 1: RMSNorm -> bf16 output
// ---------------------------------------------------------------------------
__global__ __launch_bounds__(256) void rmsnorm_kernel(const float* __restrict__ x,
                                                      const float* __restrict__ w,
                                                      unsigned short* __restrict__ h_bf) {
    int row = blockIdx.x;
    int tid = threadIdx.x;
    const float4* xr = (const float4*)(x + (size_t)row * DM);
    float4 xv = xr[tid];
    float ss = xv.x*xv.x + xv.y*xv.y + xv.z*xv.z + xv.w*xv.w;
    #pragma unroll
    for (int off = 32; off > 0; off >>= 1) ss += __shfl_down(ss, off, 64);
    __shared__ float red[4];
    if ((tid & 63) == 0) red[tid >> 6] = ss;
    __syncthreads();
    float tot = red[0] + red[1] + red[2] + red[3];
    float scale = rsqrtf(tot * (1.0f / DM) + 1e-6f);
    float4 wv = ((const float4*)w)[tid];
    ushort4 o;
    o.x = f2bf(xv.x * scale * wv.x);
    o.y = f2bf(xv.y * scale * wv.y);
    o.z = f2bf(xv.z * scale * wv.z);
    o.w = f2bf(xv.w * scale * wv.w);
    *(ushort4*)&h_bf[(size_t)row * DM + tid * 4] = o;
}

// ---------------------------------------------------------------------------
// Kernel 2: transpose + fp32->bf16.  W [K][N] fp32 -> WT [N][K] bf16.
// z selects among up to 3 (W, WT) pairs (for QKV in one dispatch).
// ---------------------------------------------------------------------------
__global__ __launch_bounds__(256) void transpose_bf16_kernel(const float* __restrict__ W0,
                                                             const float* __restrict__ W1,
                                                             const float* __restrict__ W2,
                                                             unsigned short* __restrict__ T0,
                                                             unsigned short* __restrict__ T1,
                                                             unsigned short* __restrict__ T2,
                                                             int K, int N) {
    const float* W = (blockIdx.z == 0) ? W0 : (blockIdx.z == 1) ? W1 : W2;
    unsigned short* WT = (blockIdx.z == 0) ? T0 : (blockIdx.z == 1) ? T1 : T2;
    __shared__ float tile[64][65];
    int k0 = blockIdx.y * 64, n0 = blockIdx.x * 64;
    int t = threadIdx.x;
    int r = t >> 4, c4 = (t & 15) * 4;
    #pragma unroll
    for (int i = 0; i < 4; i++) {
        float4 vv = *(const float4*)&W[(size_t)(k0 + r + i*16) * N + n0 + c4];
        tile[r + i*16][c4 + 0] = vv.x;
        tile[r + i*16][c4 + 1] = vv.y;
        tile[r + i*16][c4 + 2] = vv.z;
        tile[r + i*16][c4 + 3] = vv.w;
    }
    __syncthreads();
    int rn = t >> 2, kq = (t & 3) * 16;
    unsigned short u[16];
    #pragma unroll
    for (int i = 0; i < 16; i++) u[i] = f2bf(tile[kq + i][rn]);
    size_t base = (size_t)(n0 + rn) * K + k0 + kq;
    *(uint4*)&WT[base]     = *(uint4*)&u[0];
    *(uint4*)&WT[base + 8] = *(uint4*)&u[8];
}

// ---------------------------------------------------------------------------
// bf16 MFMA GEMM core, DOUBLE-BUFFERED LDS (one barrier per K-iter; prefetch
// tile k+1 issued before computing tile k, so the vmcnt drain at the barrier
// has a full compute phase in flight). 128x128 tile, BK=32, XOR k-chunk perm.
// Writes bf16 C (N=1024). A row-stride ldA; BT row-stride ldB; K-range
// [k0g, k0g+Klen).
// ---------------------------------------------------------------------------
__device__ __forceinline__ void gemm_core_db(const unsigned short* __restrict__ A,
                                             const unsigned short* __restrict__ BT,
                                             unsigned short* __restrict__ Cb,
                                             int ldA, int ldB, int k0g, int Klen) {
    const int N = 1024;
    __shared__ __align__(16) unsigned short As[2 * 128 * 32];
    __shared__ __align__(16) unsigned short Bs[2 * 128 * 32];
    int tid = threadIdx.x;
    int lane = tid & 63;
    int w = tid >> 6;
    int wm = (w >> 1) * 64, wn = (w & 1) * 64;
    int m0 = blockIdx.y * 128, n0 = blockIdx.x * 128;
    int hi = lane >> 4;

    f32x4 acc[4][4];
    #pragma unroll
    for (int i = 0; i < 4; i++)
        #pragma unroll
        for (int j = 0; j < 4; j++)
            acc[i][j] = (f32x4){0.f, 0.f, 0.f, 0.f};

    // stage tile 0 into buffer 0
    #pragma unroll
    for (int half = 0; half < 2; half++) {
        int c = tid + half * 256;
        int row = c >> 2, pos = c & 3;
        int kh = (pos - (row >> 1)) & 3;
        gl2lds16(A  + (size_t)(m0 + row) * ldA + k0g + kh * 8, &As[c * 8]);
        gl2lds16(BT + (size_t)(n0 + row) * ldB + k0g + kh * 8, &Bs[c * 8]);
    }

    int niter = Klen / 32;
    for (int it = 0; it < niter; it++) {
        int cur = (it & 1) * 4096;          // element offset of current buffer
        int nxt = 4096 - cur;
        __syncthreads();                    // drains prefetch into cur; protects nxt reuse
        if (it + 1 < niter) {
            int kt = k0g + (it + 1) * 32;
            #pragma unroll
            for (int half = 0; half < 2; half++) {
                int c = tid + half * 256;
                int row = c >> 2, pos = c & 3;
                int kh = (pos - (row >> 1)) & 3;
                gl2lds16(A  + (size_t)(m0 + row) * ldA + kt + kh * 8, &As[nxt + c * 8]);
                gl2lds16(BT + (size_t)(n0 + row) * ldB + kt + kh * 8, &Bs[nxt + c * 8]);
            }
        }
        bf16x8 af[4], bfr[4];
        #pragma unroll
        for (int i = 0; i < 4; i++) {
            int m = wm + i * 16 + (lane & 15);
            af[i]  = *(const bf16x8*)&As[cur + m * 32 + (((hi + (m >> 1)) & 3) * 8)];
            int n = wn + i * 16 + (lane & 15);
            bfr[i] = *(const bf16x8*)&Bs[cur + n * 32 + (((hi + (n >> 1)) & 3) * 8)];
        }
        #pragma unroll
        for (int i = 0; i < 4; i++)
            #pragma unroll
            for (int j = 0; j < 4; j++)
                acc[i][j] = __builtin_amdgcn_mfma_f32_16x16x32_bf16(af[i], bfr[j], acc[i][j], 0, 0, 0);
    }
    #pragma unroll
    for (int i = 0; i < 4; i++) {
        #pragma unroll
        for (int j = 0; j < 4; j++) {
            int col = n0 + wn + j * 16 + (lane & 15);
            #pragma unroll
            for (int r = 0; r < 4; r++) {
                int row = m0 + wm + i * 16 + hi * 4 + r;
                Cb[(size_t)row * N + col] = f2bf(acc[i][j][r]);
            }
        }
    }
}

__global__ __launch_bounds__(256) void gemm_qkv_mfma(const unsigned short* __restrict__ A,
                                                     const unsigned short* __restrict__ BT0,
                                                     const unsigned short* __restrict__ BT1,
                                                     const unsigned short* __restrict__ BT2,
                                                     unsigned short* __restrict__ C0,
                                                     unsigned short* __restrict__ C1,
                                                     unsigned short* __restrict__ C2) {
    const unsigned short* BT = (blockIdx.z == 0) ? BT0 : (blockIdx.z == 1) ? BT1 : BT2;
    unsigned short* C = (blockIdx.z == 0) ? C0 : (blockIdx.z == 1) ? C1 : C2;
    gemm_core_db(A, BT, C, 1024, 1024, 0, 1024);
}

// Output GEMM, split-K=2: z-half computes bf16 partial P[z] over K-range z*1024.
__global__ __launch_bounds__(256) void gemm_out_mfma(const unsigned short* __restrict__ A,
                                                     const unsigned short* __restrict__ BT,
                                                     unsigned short* __restrict__ P0,
                                                     unsigned short* __restrict__ P1) {
    unsigned short* P = (blockIdx.z == 0) ? P0 : P1;
    gemm_core_db(A, BT, P, 2048, 2048, blockIdx.z * 1024, 1024);
}

// Reduce: out = x + P0 + P1   (float4-vectorized)
__global__ __launch_bounds__(256) void out_reduce_kernel(const float* __restrict__ x,
                                                         const unsigned short* __restrict__ P0,
                                                         const unsigned short* __restrict__ P1,
                                                         float* __restrict__ out) {
    int g = blockIdx.x * 256 + threadIdx.x;      // over 4M/4 vec4 groups
    size_t e = (size_t)g * 4;
    float4 xv = *(const float4*)&x[e];
    ushort4 a = *(const ushort4*)&P0[e];
    ushort4 b = *(const ushort4*)&P1[e];
    float4 o;
    o.x = xv.x + bf2f(a.x) + bf2f(b.x);
    o.y = xv.y + bf2f(a.y) + bf2f(b.y);
    o.z = xv.z + bf2f(a.z) + bf2f(b.z);
    o.w = xv.w + bf2f(a.w) + bf2f(b.w);
    *(float4*)&out[e] = o;
}

// ---------------------------------------------------------------------------
// Kernel 3: feature projection (bf16 in, bf16 out)
// ---------------------------------------------------------------------------
__global__ __launch_bounds__(256) void feat_kernel(const unsigned short* __restrict__ qb,
                                                   const unsigned short* __restrict__ kb,
                                                   const float* __restrict__ Wqf,
                                                   const float* __restrict__ Wkf,
                                                   unsigned short* __restrict__ qf,
                                                   unsigned short* __restrict__ kf) {
    __shared__ float Wl[HD * FEAT];
    const unsigned short* src = blockIdx.z ? kb : qb;
    const float* Wm = blockIdx.z ? Wkf : Wqf;
    unsigned short* dst = blockIdx.z ? kf : qf;
    int tid = threadIdx.x;
    ((float4*)Wl)[tid] = ((const float4*)Wm)[tid];
    __syncthreads();
    int gid = blockIdx.x * 256 + tid;
    int f = gid & 15;
    int rowh = gid >> 4;
    const unsigned short* s = src + (size_t)rowh * HD;
    float acc = 0.f;
    #pragma unroll
    for (int d = 0; d < HD; d++) acc += bf2f(s[d]) * Wl[d * FEAT + f];
    dst[gid] = f2bf(acc);
}

// ---------------------------------------------------------------------------
// Kernel 4: sliding-window attention, single-shot MFMA flash tile.
// ---------------------------------------------------------------------------
__global__ __launch_bounds__(256) void win_mfma_kernel(const unsigned short* __restrict__ q_bf,
                                                       const unsigned short* __restrict__ k_bf,
                                                       const unsigned short* __restrict__ v_bf,
                                                       unsigned short* __restrict__ cat_bf) {
    int qtile = blockIdx.x;
    int bh = blockIdx.y;
    int h = bh & 15;
    int b = bh >> 4;
    int tid = threadIdx.x;
    int lane = tid & 63;
    int wv = tid >> 6;
    int qr0 = wv * 16;
    int t0 = qtile * 64;
    int k0 = t0 - 64;

    __shared__ __align__(16) unsigned short Qs[64 * 64];
    __shared__ __align__(16) unsigned short Ks[128 * 64];
    __shared__ __align__(16) unsigned short Vt[64 * 128];
    __shared__ __align__(16) unsigned short Pl[64 * 128];

    #pragma unroll
    for (int half = 0; half < 2; half++) {
        int slot = tid + half * 256;
        int row = slot >> 3, pos = slot & 7;
        int o = (pos - row) & 7;
        gl2lds16(q_bf + (size_t)(b * TT + t0 + row) * (NH * HD) + h * HD + o * 8,
                 &Qs[slot * 8]);
    }
    #pragma unroll
    for (int qd = 0; qd < 4; qd++) {
        int slot = tid + qd * 256;
        int row = slot >> 3, pos = slot & 7;
        int o = (pos - row) & 7;
        int kg = k0 + row;
        if (kg >= 0) {
            gl2lds16(k_bf + (size_t)(b * TT + kg) * (NH * HD) + h * HD + o * 8,
                     &Ks[slot * 8]);
        } else {
            uint4 z = {0, 0, 0, 0};
            *(uint4*)&Ks[slot * 8] = z;
        }
    }
    {
        int kk = tid & 127;
        int dh = tid >> 7;
        int kg = k0 + kk;
        unsigned short tmp[32];
        if (kg >= 0) {
            size_t base = (size_t)(b * TT + kg) * (NH * HD) + h * HD + dh * 32;
            *(uint4*)&tmp[0]  = *(const uint4*)&v_bf[base];
            *(uint4*)&tmp[8]  = *(const uint4*)&v_bf[base + 8];
            *(uint4*)&tmp[16] = *(const uint4*)&v_bf[base + 16];
            *(uint4*)&tmp[24] = *(const uint4*)&v_bf[base + 24];
        } else {
            #pragma unroll
            for (int d = 0; d < 32; d++) tmp[d] = 0;
        }
        int o = kk >> 3, klow = kk & 7;
        #pragma unroll
        for (int d = 0; d < 32; d++) {
            int dim = dh * 32 + d;
            Vt[dim * 128 + ((o + dim) & 15) * 8 + klow] = tmp[d];
        }
    }
    __syncthreads();

    int hi = lane >> 4;
    int lan15 = lane & 15;
    f32x4 sc[8];
    #pragma unroll
    for (int nt = 0; nt < 8; nt++) sc[nt] = (f32x4){0.f, 0.f, 0.f, 0.f};
    #pragma unroll
    for (int ks = 0; ks < 2; ks++) {
        int m = qr0 + lan15;
        int oA = ks * 4 + hi;
        bf16x8 a = *(const bf16x8*)&Qs[m * 64 + ((oA + m) & 7) * 8];
        #pragma unroll
        for (int nt = 0; nt < 8; nt++) {
            int n = nt * 16 + lan15;
            bf16x8 bb = *(const bf16x8*)&Ks[n * 64 + ((oA + n) & 7) * 8];
            sc[nt] = __builtin_amdgcn_mfma_f32_16x16x32_bf16(a, bb, sc[nt], 0, 0, 0);
        }
    }

    float lrow[4];
    #pragma unroll
    for (int r = 0; r < 4; r++) {
        int tq = t0 + qr0 + hi * 4 + r;
        float mx = -1e30f;
        #pragma unroll
        for (int nt = 0; nt < 8; nt++) {
            int s = k0 + nt * 16 + lan15;
            bool ok = (s >= 0) && (s <= tq) && (s >= tq - WIN);
            float vv = ok ? sc[nt][r] * 0.125f : -1e30f;
            sc[nt][r] = vv;
            mx = fmaxf(mx, vv);
        }
        #pragma unroll
        for (int off = 1; off < 16; off <<= 1) mx = fmaxf(mx, __shfl_xor(mx, off, 64));
        float ls = 0.f;
        #pragma unroll
        for (int nt = 0; nt < 8; nt++) {
            float e = __expf(sc[nt][r] - mx);
            sc[nt][r] = e;
            ls += e;
        }
        #pragma unroll
        for (int off = 1; off < 16; off <<= 1) ls += __shfl_xor(ls, off, 64);
        lrow[r] = ls;
    }

    #pragma unroll
    for (int nt = 0; nt < 8; nt++) {
        #pragma unroll
        for (int r = 0; r < 4; r++) {
            int row = qr0 + hi * 4 + r;
            int col = nt * 16 + lan15;
            Pl[row * 128 + (((col >> 3) + row) & 15) * 8 + (col & 7)] = f2bf(sc[nt][r]);
        }
    }
    __syncthreads();

    f32x4 y[4];
    #pragma unroll
    for (int nt = 0; nt < 4; nt++) y[nt] = (f32x4){0.f, 0.f, 0.f, 0.f};
    #pragma unroll
    for (int ks = 0; ks < 4; ks++) {
        int m = qr0 + lan15;
        int oA = ks * 4 + hi;
        bf16x8 a = *(const bf16x8*)&Pl[m * 128 + ((oA + m) & 15) * 8];
        #pragma unroll
        for (int nt = 0; nt < 4; nt++) {
            int n = nt * 16 + lan15;
            bf16x8 bb = *(const bf16x8*)&Vt[n * 128 + ((oA + n) & 15) * 8];
            y[nt] = __builtin_amdgcn_mfma_f32_16x16x32_bf16(a, bb, y[nt], 0, 0, 0);
        }
    }

    #pragma unroll
    for (int nt = 0; nt < 4; nt++) {
        #pragma unroll
        for (int r = 0; r < 4; r++) {
            int row = qr0 + hi * 4 + r;
            int dim = nt * 16 + lan15;
            cat_bf[(size_t)(b * TT + t0 + row) * (2 * DM) + DM + h * HD + dim] =
                f2bf(y[nt][r] / lrow[r]);
        }
    }
}

// ---------------------------------------------------------------------------
// Linear attention, phi-space chunked (CHUNK=64, PHI=153 padded to 160)
// ---------------------------------------------------------------------------
#define PHI 160
#define NCH 32
#define KVROWS 65
#define CH_STRIDE ((size_t)32 * KVROWS * PHI)

// Phase B: per-chunk KV^T via MFMA.  grid (32 chunks, 32 bh)
__global__ __launch_bounds__(256) void lin_kv_kernel(const unsigned short* __restrict__ kf,
                                                     const unsigned short* __restrict__ v_bf,
                                                     unsigned short* __restrict__ kvbuf) {
    int c = blockIdx.x, bh = blockIdx.y;
    int h = bh & 15, b = bh >> 4;
    int tid = threadIdx.x, lane = tid & 63, w = tid >> 6;
    int hi = lane >> 4, l15 = lane & 15;

    __shared__ unsigned short kf_l[64 * 16];
    __shared__ __align__(16) unsigned short PhiT[192 * 66];
    __shared__ __align__(16) unsigned short Vt[80 * 66];
    __shared__ int iu[136], ju[136];
    __shared__ float sclut[136];

    if (tid < 136) {
        int qq = tid, i = 0;
        while (qq >= 16 - i) { qq -= 16 - i; i++; }
        iu[tid] = i; ju[tid] = i + qq;
        sclut[tid] = (qq == 0) ? 0.5f : 0.70710678118654752f;
    }
    {
        int r = tid >> 2, f4 = (tid & 3) * 4;
        *(ushort4*)&kf_l[r * 16 + f4] =
            *(const ushort4*)&kf[((size_t)((b * TT + c * 64 + r) * NH + h)) * FEAT + f4];
    }
    {
        int p = tid & 31, dq = (tid >> 5) * 8;
        size_t base0 = ((size_t)(b * TT + c * 64 + 2 * p)) * DM + h * HD + dq;
        unsigned short a[8], bq[8];
        *(uint4*)a  = *(const uint4*)&v_bf[base0];
        *(uint4*)bq = *(const uint4*)&v_bf[base0 + DM];
        #pragma unroll
        for (int d = 0; d < 8; d++) {
            ushort2 u; u.x = a[d]; u.y = bq[d];
            *(ushort2*)&Vt[(dq + d) * 66 + 2 * p] = u;
        }
        #pragma unroll
        for (int i = 0; i < 4; i++) {
            int e = tid + i * 256;
            Vt[(64 + (e >> 6)) * 66 + (e & 63)] = 0x3F80;
        }
    }
    __syncthreads();
    {
        int s = tid & 63, fb = tid >> 6;
        float xr[16];
        #pragma unroll
        for (int i = 0; i < 16; i++) xr[i] = bf2f(kf_l[s * 16 + i]);
        for (int it = 0; it < 48; it++) {
            int f = fb + it * 4;
            float val;
            if (f == 0) val = 1.f;
            else if (f < 17) val = xr[f - 1];
            else if (f < 153) { int qq = f - 17; val = xr[iu[qq]] * xr[ju[qq]] * sclut[qq]; }
            else val = 0.f;
            PhiT[f * 66 + s] = f2bf(val);
        }
    }
    __syncthreads();
    f32x4 acc[5][3];
    #pragma unroll
    for (int m = 0; m < 5; m++)
        #pragma unroll
        for (int j = 0; j < 3; j++) acc[m][j] = (f32x4){0.f, 0.f, 0.f, 0.f};
    #pragma unroll
    for (int ks = 0; ks < 2; ks++) {
        bf16x8 bfrag[3];
        #pragma unroll
        for (int j = 0; j < 3; j++)
            bfrag[j] = *(const bf16x8*)&PhiT[((3 * w + j) * 16 + l15) * 66 + ks * 32 + hi * 8];
        #pragma unroll
        for (int m = 0; m < 5; m++) {
            bf16x8 afrag = *(const bf16x8*)&Vt[(m * 16 + l15) * 66 + ks * 32 + hi * 8];
            #pragma unroll
            for (int j = 0; j < 3; j++)
                acc[m][j] = __builtin_amdgcn_mfma_f32_16x16x32_bf16(afrag, bfrag[j], acc[m][j], 0, 0, 0);
        }
    }
    size_t obase = ((size_t)c * 32 + bh) * (KVROWS * PHI);
    #pragma unroll
    for (int m = 0; m < 5; m++) {
        #pragma unroll
        for (int j = 0; j < 3; j++) {
            int f = (3 * w + j) * 16 + l15;
            if (f >= PHI) continue;
            #pragma unroll
            for (int r = 0; r < 4; r++) {
                int row = m * 16 + hi * 4 + r;
                if (row >= KVROWS) continue;
                kvbuf[obase + row * PHI + f] = f2bf(acc[m][j][r]);
            }
        }
    }
}

// Phase C: in-place exclusive prefix over chunks. grid (41, 32 bh)
__global__ __launch_bounds__(256) void lin_scan_kernel(unsigned short* __restrict__ kvbuf) {
    int e = blockIdx.x * 256 + threadIdx.x;
    int bh = blockIdx.y;
    if (e >= KVROWS * PHI) return;
    float acc = 0.f;
    size_t off = (size_t)bh * (KVROWS * PHI) + e;
    for (int c = 0; c < NCH; c++) {
        float vv = bf2f(kvbuf[off]);
        kvbuf[off] = f2bf(acc);
        acc += vv;
        off += CH_STRIDE;
    }
}

// Phase D: outputs. grid (32 chunks, 32 bh).
__global__ __launch_bounds__(256) void lin_out_kernel(const unsigned short* __restrict__ qf,
                                                      const unsigned short* __restrict__ kf,
                                                      const unsigned short* __restrict__ v_bf,
                                                      const unsigned short* __restrict__ kvbuf,
                                                      unsigned short* __restrict__ cat_bf) {
    int c = blockIdx.x, bh = blockIdx.y;
    int h = bh & 15, b = bh >> 4;
    int tid = threadIdx.x, lane = tid & 63, w = tid >> 6;
    int hi = lane >> 4, l15 = lane & 15;

    __shared__ __align__(16) unsigned short kf_lb[64 * 34];
    __shared__ __align__(16) unsigned short KVS_l[80 * 162];
    __shared__ __align__(16) unsigned short Vt[80 * 66];
    __shared__ __align__(16) unsigned short P_l[64 * 66];
    __shared__ int iu[136], ju[136];
    __shared__ float sclut[136];

    if (tid < 136) {
        int qq = tid, i = 0;
        while (qq >= 16 - i) { qq -= 16 - i; i++; }
        iu[tid] = i; ju[tid] = i + qq;
        sclut[tid] = (qq == 0) ? 0.5f : 0.70710678118654752f;
    }
    {
        int r = tid >> 2, f4 = (tid & 3) * 4;
        *(ushort4*)&kf_lb[r * 34 + f4] =
            *(const ushort4*)&kf[((size_t)((b * TT + c * 64 + r) * NH + h)) * FEAT + f4];
        ushort4 z4 = {0, 0, 0, 0};
        *(ushort4*)&kf_lb[r * 34 + 16 + f4] = z4;
    }
    {
        int p = tid & 31, dq = (tid >> 5) * 8;
        size_t base0 = ((size_t)(b * TT + c * 64 + 2 * p)) * DM + h * HD + dq;
        unsigned short a[8], bq[8];
        *(uint4*)a  = *(const uint4*)&v_bf[base0];
        *(uint4*)bq = *(const uint4*)&v_bf[base0 + DM];
        #pragma unroll
        for (int d = 0; d < 8; d++) {
            ushort2 u; u.x = a[d]; u.y = bq[d];
            *(ushort2*)&Vt[(dq + d) * 66 + 2 * p] = u;
        }
        #pragma unroll
        for (int i = 0; i < 4; i++) {
            int e = tid + i * 256;
            Vt[(64 + (e >> 6)) * 66 + (e & 63)] = 0x3F80;
        }
    }
    {
        size_t gbase = ((size_t)c * 32 + bh) * (KVROWS * PHI);
        #pragma unroll
        for (int i = 0; i < 11; i++) {
            int e4 = tid + i * 256;
            if (e4 < KVROWS * 40) {
                int r = e4 / 40, f4 = (e4 % 40) * 4;
                *(ushort4*)&KVS_l[r * 162 + f4] =
                    *(const ushort4*)&kvbuf[gbase + r * PHI + f4];
            }
        }
        #pragma unroll
        for (int i = 0; i < 3; i++) {
            int e4 = tid + i * 256;
            if (e4 < 15 * 40) {
                int r = 65 + e4 / 40, f4 = (e4 % 40) * 4;
                ushort4 z4 = {0, 0, 0, 0};
                *(ushort4*)&KVS_l[r * 162 + f4] = z4;
            }
        }
    }
    int t_m = w * 16 + l15;
    float xr[16];
    {
        unsigned short qr[16];
        size_t qb = ((size_t)((b * TT + c * 64 + t_m) * NH + h)) * FEAT;
        *(ushort4*)&qr[0]  = *(const ushort4*)&qf[qb];
        *(ushort4*)&qr[4]  = *(const ushort4*)&qf[qb + 4];
        *(ushort4*)&qr[8]  = *(const ushort4*)&qf[qb + 8];
        *(ushort4*)&qr[12] = *(const ushort4*)&qf[qb + 12];
        #pragma unroll
        for (int i = 0; i < 16; i++) xr[i] = bf2f(qr[i]);
    }
    __syncthreads();

    f32x4 acc[5];
    #pragma unroll
    for (int n = 0; n < 5; n++) acc[n] = (f32x4){0.f, 0.f, 0.f, 0.f};

    #pragma unroll
    for (int ks = 0; ks < 5; ks++) {
        union { unsigned short u[8]; bf16x8 v; } af;
        int f0 = ks * 32 + hi * 8;
        #pragma unroll
        for (int j = 0; j < 8; j++) {
            int f = f0 + j;
            float val;
            if (f == 0) val = 1.f;
            else if (f < 17) val = xr[f - 1];
            else { int qq = f - 17; val = xr[iu[qq]] * xr[ju[qq]] * sclut[qq]; }
            af.u[j] = f2bf(val);
        }
        #pragma unroll
        for (int n = 0; n < 5; n++) {
            bf16x8 bb = *(const bf16x8*)&KVS_l[(n * 16 + l15) * 162 + ks * 32 + hi * 8];
            acc[n] = __builtin_amdgcn_mfma_f32_16x16x32_bf16(af.v, bb, acc[n], 0, 0, 0);
        }
    }

    {
        union { unsigned short u[8]; bf16x8 v; } aq;
        int f0 = hi * 8;
        #pragma unroll
        for (int j = 0; j < 8; j++) {
            int f = f0 + j;
            aq.u[j] = (f < 16) ? f2bf(xr[f]) : (unsigned short)0;
        }
        #pragma unroll
        for (int n = 0; n < 4; n++) {
            bf16x8 bk = *(const bf16x8*)&kf_lb[(n * 16 + l15) * 34 + hi * 8];
            f32x4 zv = {0.f, 0.f, 0.f, 0.f};
            f32x4 sc = __builtin_amdgcn_mfma_f32_16x16x32_bf16(aq.v, bk, zv, 0, 0, 0);
            int sl = n * 16 + l15;
            #pragma unroll
            for (int r = 0; r < 4; r++) {
                int rl = w * 16 + hi * 4 + r;
                float sv = 1.f + 0.5f * sc[r];
                sv = sv * sv;
                if (sl > rl) sv = 0.f;
                P_l[rl * 66 + sl] = f2bf(sv);
            }
        }
    }
    __syncthreads();

    #pragma unroll
    for (int ks = 0; ks < 2; ks++) {
        bf16x8 a = *(const bf16x8*)&P_l[(w * 16 + l15) * 66 + ks * 32 + hi * 8];
        #pragma unroll
        for (int n = 0; n < 5; n++) {
            bf16x8 bb = *(const bf16x8*)&Vt[(n * 16 + l15) * 66 + ks * 32 + hi * 8];
            acc[n] = __builtin_amdgcn_mfma_f32_16x16x32_bf16(a, bb, acc[n], 0, 0, 0);
        }
    }

    #pragma unroll
    for (int r = 0; r < 4; r++) {
        float zz = __shfl(acc[4][r], (lane & 48), 64);
        int token = c * 64 + w * 16 + hi * 4 + r;
        #pragma unroll
        for (int n = 0; n < 4; n++) {
            int d = n * 16 + l15;
            cat_bf[((size_t)(b * TT + token)) * (2 * DM) + h * HD + d] =
                f2bf(acc[n][r] / (zz + 1e-6f));
        }
    }
}

// ---------------------------------------------------------------------------
extern "C" void kernel_launch(void* const* d_in, const int* in_sizes, int n_in,
                              void* d_out, int out_size, void* d_ws, size_t ws_size,
                              hipStream_t stream) {
    const float* x      = (const float*)d_in[0];
    const float* norm_w = (const float*)d_in[1];
    const float* Wq     = (const float*)d_in[2];
    const float* Wk     = (const float*)d_in[3];
    const float* Wv     = (const float*)d_in[4];
    const float* Wqf    = (const float*)d_in[5];
    const float* Wkf    = (const float*)d_in[6];
    const float* Wout   = (const float*)d_in[7];
    float* out = (float*)d_out;

    char* p = (char*)d_ws;
    unsigned short* h_bf = (unsigned short*)p; p += (size_t)RTOT * DM * 2;       // 8 MB
    unsigned short* WqT  = (unsigned short*)p; p += (size_t)DM * DM * 2;         // 2 MB
    unsigned short* WkT  = (unsigned short*)p; p += (size_t)DM * DM * 2;
    unsigned short* WvT  = (unsigned short*)p; p += (size_t)DM * DM * 2;
    unsigned short* WoT  = (unsigned short*)p; p += (size_t)DM * 2 * DM * 2;     // 4 MB
    unsigned short* q_bf = (unsigned short*)p; p += (size_t)RTOT * DM * 2;       // 8 MB
    unsigned short* k_bf = (unsigned short*)p; p += (size_t)RTOT * DM * 2;
    unsigned short* v_bf = (unsigned short*)p; p += (size_t)RTOT * DM * 2;
    unsigned short* qf_bf = (unsigned short*)p; p += (size_t)RTOT * NH * FEAT * 2; // 2 MB
    unsigned short* kf_bf = (unsigned short*)p; p += (size_t)RTOT * NH * FEAT * 2;
    unsigned short* cat_bf = (unsigned short*)p; p += (size_t)RTOT * 2 * DM * 2;   // 16 MB
    unsigned short* kvbuf  = (unsigned short*)p; p += (size_t)NCH * 32 * KVROWS * PHI * 2; // 21.3 MB
    unsigned short* P0 = (unsigned short*)p; p += (size_t)RTOT * DM * 2;           // 8 MB
    unsigned short* P1 = (unsigned short*)p; p += (size_t)RTOT * DM * 2;           // 8 MB

    rmsnorm_kernel<<<RTOT, 256, 0, stream>>>(x, norm_w, h_bf);
    transpose_bf16_kernel<<<dim3(16, 16, 3), 256, 0, stream>>>(Wq, Wk, Wv, WqT, WkT, WvT, 1024, 1024);
    transpose_bf16_kernel<<<dim3(16, 32, 1), 256, 0, stream>>>(Wout, Wout, Wout, WoT, WoT, WoT, 2048, 1024);
    gemm_qkv_mfma<<<dim3(8, 32, 3), 256, 0, stream>>>(h_bf, WqT, WkT, WvT, q_bf, k_bf, v_bf);
    feat_kernel<<<dim3((RTOT * NH * FEAT) / 256, 1, 2), 256, 0, stream>>>(q_bf, k_bf, Wqf, Wkf, qf_bf, kf_bf);
    win_mfma_kernel<<<dim3(TT / 64, BB * NH), 256, 0, stream>>>(q_bf, k_bf, v_bf, cat_bf);
    lin_kv_kernel<<<dim3(NCH, BB * NH), 256, 0, stream>>>(kf_bf, v_bf, kvbuf);
    lin_scan_kernel<<<dim3((KVROWS * PHI + 255) / 256, BB * NH), 256, 0, stream>>>(kvbuf);
    lin_out_kernel<<<dim3(NCH, BB * NH), 256, 0, stream>>>(qf_bf, kf_bf, v_bf, kvbuf, cat_bf);
    gemm_out_mfma<<<dim3(8, 32, 2), 256, 0, stream>>>(cat_bf, WoT, P0, P1);
    out_reduce_kernel<<<RTOT * DM / 1024, 256, 0, stream>>>(x, P0, P1, out);
}